// Round 3
// baseline (534.657 us; speedup 1.0000x reference)
//
#include <hip/hip_runtime.h>
#include <hip/hip_fp16.h>

#define Bx 2
#define Cx 256
#define Hx 128
#define Wx 128
#define HWx (Hx*Wx)     // 16384
#define Ox 256
#define Kx 9
#define NOFF 27         // 3*K offset-conv output channels

// ws layout (float offsets):
//   tmp   [0, 884736)            B*27*HW
//   w_t   [884736, 946944)       27*256*9 transposed to [c][oc][t]
//   stats [946944, 947008)       18*2 (max, 1/sum) padded
//   agg   [947008, 947008+8388608)

// init tmp with bias (conv accumulates on top via atomics)
__global__ void k_init(const float* __restrict__ b_off, float* __restrict__ p, int n) {
    int i = blockIdx.x * 256 + threadIdx.x;
    if (i < n) p[i] = b_off[(i / HWx) % NOFF];
}

__global__ void k_wtr(const float* __restrict__ w_off, float* __restrict__ w_t) {
    int i = blockIdx.x * 256 + threadIdx.x;
    if (i >= NOFF * Cx * 9) return;
    int oc = i / (Cx * 9);
    int r  = i % (Cx * 9);
    int c  = r / 9;
    int t  = r % 9;
    w_t[(c * NOFF + oc) * 9 + t] = w_off[i];
}

// 3x3 conv C=256 -> 27, pad 1. Thread per pixel, 16 c-chunks of 16 channels.
// grid (HW/256, B, 16). Taps direct from global (L1-hot), weights scalar-loaded.
__global__ __launch_bounds__(256) void k1_offconv(
        const float* __restrict__ x, const float* __restrict__ w_t,
        float* __restrict__ tmp) {
    int tid = threadIdx.x;
    int hw  = blockIdx.x * 256 + tid;
    int b   = blockIdx.y;
    int cc  = blockIdx.z;             // 0..15
    int y   = hw >> 7;
    int xx  = hw & (Wx - 1);

    float acc[NOFF];
#pragma unroll
    for (int oc = 0; oc < NOFF; oc++) acc[oc] = 0.f;

    const float* xb = x + ((b * Cx) + cc * 16) * HWx;
    const float* wc = w_t + (cc * 16) * (NOFF * 9);

    for (int ci = 0; ci < 16; ci++) {
        float t[9];
#pragma unroll
        for (int dy = -1; dy <= 1; dy++) {
            int yy = y + dy;
            bool vy = (yy >= 0) & (yy < Hx);
            int cy = min(max(yy, 0), Hx - 1);
#pragma unroll
            for (int dx = -1; dx <= 1; dx++) {
                int xq = xx + dx;
                bool v = vy & (xq >= 0) & (xq < Wx);
                int cx = min(max(xq, 0), Wx - 1);
                float val = xb[cy * Wx + cx];
                t[(dy + 1) * 3 + (dx + 1)] = v ? val : 0.f;
            }
        }
#pragma unroll
        for (int oc = 0; oc < NOFF; oc++) {
            acc[oc] += wc[oc * 9 + 0] * t[0] + wc[oc * 9 + 1] * t[1] + wc[oc * 9 + 2] * t[2]
                     + wc[oc * 9 + 3] * t[3] + wc[oc * 9 + 4] * t[4] + wc[oc * 9 + 5] * t[5]
                     + wc[oc * 9 + 6] * t[6] + wc[oc * 9 + 7] * t[7] + wc[oc * 9 + 8] * t[8];
        }
        xb += HWx;
        wc += NOFF * 9;
    }
#pragma unroll
    for (int oc = 0; oc < NOFF; oc++)
        atomicAdd(&tmp[((b * NOFF + oc) * HWx) + hw], acc[oc]);
}

// Per-(b,k) spatial softmax stats over HW: stats[bk*2]=max, stats[bk*2+1]=1/sum(exp(v-max))
__global__ __launch_bounds__(256) void k2_softmax(
        const float* __restrict__ tmp, float* __restrict__ stats) {
    int bk = blockIdx.x;              // 0..17
    int b = bk / Kx, k = bk % Kx;
    const float* p = tmp + ((b * NOFF) + 2 * Kx + k) * HWx;
    __shared__ float red[256];
    int tid = threadIdx.x;
    float mx = -1e30f;
    for (int i = tid; i < HWx; i += 256) mx = fmaxf(mx, p[i]);
    red[tid] = mx; __syncthreads();
    for (int s = 128; s > 0; s >>= 1) {
        if (tid < s) red[tid] = fmaxf(red[tid], red[tid + s]);
        __syncthreads();
    }
    mx = red[0]; __syncthreads();
    float sm = 0.f;
    for (int i = tid; i < HWx; i += 256) sm += __expf(p[i] - mx);
    red[tid] = sm; __syncthreads();
    for (int s = 128; s > 0; s >>= 1) {
        if (tid < s) red[tid] += red[tid + s];
        __syncthreads();
    }
    if (tid == 0) { stats[bk * 2] = mx; stats[bk * 2 + 1] = 1.f / red[0]; }
}

// Bilinear sample * softmax mask, summed over k -> agg[b,c,h,w].
// Thread = pixel; grid (HW/256, B, 8 c-chunks of 32).
// Coefficients packed: 18 half2 weights (x256 scale), 18 ushort2 byte-offsets.
// Inner loop interleaves 4 channels (independent accumulators, shared unpack).
__global__ __launch_bounds__(256) void k3_sample(
        const float* __restrict__ x, const float* __restrict__ tmp,
        const float* __restrict__ stats, float* __restrict__ agg) {
    int tid = threadIdx.x;
    int hw  = blockIdx.x * 256 + tid;
    int b   = blockIdx.y;
    int c0  = blockIdx.z * 32;
    int y   = hw >> 7;
    int xx  = hw & (Wx - 1);

    unsigned int cwp[18];   // half2 packed weights (pre-scaled by 256)
    unsigned int cop[18];   // ushort2 packed byte offsets into the channel plane

#pragma unroll
    for (int k = 0; k < Kx; k++) {
        float dy = tmp[((b * NOFF) + 2 * k) * HWx + hw];
        float dx = tmp[((b * NOFF) + 2 * k + 1) * HWx + hw];
        float lg = tmp[((b * NOFF) + 2 * Kx + k) * HWx + hw];
        float m  = __expf(lg - stats[(b * Kx + k) * 2]) * stats[(b * Kx + k) * 2 + 1] * 256.f;
        float py = dy + (float)(k / 3 - 1 + y);
        float px = dx + (float)(k % 3 - 1 + xx);
        float fy = floorf(py), fx = floorf(px);
        int y0 = (int)fy, x0 = (int)fx;
        float ly = py - fy, lx = px - fx;
        float w00 = (1.f - ly) * (1.f - lx) * m;
        float w01 = (1.f - ly) * lx * m;
        float w10 = ly * (1.f - lx) * m;
        float w11 = ly * lx * m;
        int y1 = y0 + 1, x1 = x0 + 1;
        bool vy0 = (y0 >= 0) & (y0 < Hx), vy1 = (y1 >= 0) & (y1 < Hx);
        bool vx0 = (x0 >= 0) & (x0 < Wx), vx1 = (x1 >= 0) & (x1 < Wx);
        int cy0 = min(max(y0, 0), Hx - 1), cy1 = min(max(y1, 0), Hx - 1);
        int cx0 = min(max(x0, 0), Wx - 1), cx1 = min(max(x1, 0), Wx - 1);
        float a00 = (vy0 && vx0) ? w00 : 0.f;
        float a01 = (vy0 && vx1) ? w01 : 0.f;
        float a10 = (vy1 && vx0) ? w10 : 0.f;
        float a11 = (vy1 && vx1) ? w11 : 0.f;
        unsigned int o00 = (unsigned int)((cy0 * Wx + cx0) * 4);
        unsigned int o01 = (unsigned int)((cy0 * Wx + cx1) * 4);
        unsigned int o10 = (unsigned int)((cy1 * Wx + cx0) * 4);
        unsigned int o11 = (unsigned int)((cy1 * Wx + cx1) * 4);
        __half2 h0 = __halves2half2(__float2half_rn(a00), __float2half_rn(a01));
        __half2 h1 = __halves2half2(__float2half_rn(a10), __float2half_rn(a11));
        cwp[2 * k]     = *(unsigned int*)&h0;
        cwp[2 * k + 1] = *(unsigned int*)&h1;
        cop[2 * k]     = o00 | (o01 << 16);
        cop[2 * k + 1] = o10 | (o11 << 16);
    }

    const char* xb = (const char*)(x + ((b * Cx) + c0) * HWx);
    float* ab = agg + ((b * Cx) + c0) * HWx + hw;
#pragma unroll 1
    for (int cg = 0; cg < 8; cg++) {
        const char* p0 = xb;
        const char* p1 = xb + HWx * 4;
        const char* p2 = xb + HWx * 8;
        const char* p3 = xb + HWx * 12;
        float a0 = 0.f, a1 = 0.f, a2 = 0.f, a3 = 0.f;
#pragma unroll
        for (int i = 0; i < 18; i++) {
            unsigned int oo = cop[i];
            unsigned int ww = cwp[i];
            unsigned int off0 = oo & 0xFFFFu;
            unsigned int off1 = oo >> 16;
            float2 wf = __half22float2(*(const __half2*)&ww);
            a0 += wf.x * *(const float*)(p0 + off0);
            a1 += wf.x * *(const float*)(p1 + off0);
            a2 += wf.x * *(const float*)(p2 + off0);
            a3 += wf.x * *(const float*)(p3 + off0);
            a0 += wf.y * *(const float*)(p0 + off1);
            a1 += wf.y * *(const float*)(p1 + off1);
            a2 += wf.y * *(const float*)(p2 + off1);
            a3 += wf.y * *(const float*)(p3 + off1);
        }
        const float s = 1.f / 256.f;
        ab[0]        = a0 * s;
        ab[HWx]      = a1 * s;
        ab[HWx * 2]  = a2 * s;
        ab[HWx * 3]  = a3 * s;
        xb += HWx * 16;
        ab += HWx * 4;
    }
}

// out[b,o,hw] = bias[o] + sum_c weight[o,c] * agg[b,c,hw]
// Tile 64(o) x 64(hw), 256 threads, 4x4 per thread, K-step 16.
__global__ __launch_bounds__(256) void k4_gemm(
        const float* __restrict__ agg, const float* __restrict__ weight,
        const float* __restrict__ bias, float* __restrict__ out) {
    int b  = blockIdx.z;
    int o0 = blockIdx.y * 64;
    int n0 = blockIdx.x * 64;
    __shared__ float At[16][64];      // [k][hw]
    __shared__ float Wt[16][68];      // [k][o], padded for alignment/banks
    int tid = threadIdx.x;
    int tx = tid & 15;                // hw quad
    int ty = tid >> 4;                // o quad
    float acc[4][4];
#pragma unroll
    for (int i = 0; i < 4; i++)
#pragma unroll
        for (int j = 0; j < 4; j++) acc[i][j] = 0.f;

    for (int k0 = 0; k0 < Cx; k0 += 16) {
        {
            int kk = tid >> 6;        // 0..3
            int j  = tid & 63;
#pragma unroll
            for (int r = 0; r < 4; r++)
                At[kk + 4 * r][j] = agg[((b * Cx) + k0 + kk + 4 * r) * HWx + n0 + j];
        }
        {
            int ki = tid & 15;
            int oi = tid >> 4;        // 0..15
#pragma unroll
            for (int r = 0; r < 4; r++)
                Wt[ki][oi + 16 * r] = weight[(o0 + oi + 16 * r) * Cx + k0 + ki];
        }
        __syncthreads();
#pragma unroll
        for (int k = 0; k < 16; k++) {
            float a[4], w[4];
#pragma unroll
            for (int j = 0; j < 4; j++) a[j] = At[k][4 * tx + j];
#pragma unroll
            for (int i = 0; i < 4; i++) w[i] = Wt[k][4 * ty + i];
#pragma unroll
            for (int i = 0; i < 4; i++)
#pragma unroll
                for (int j = 0; j < 4; j++) acc[i][j] += w[i] * a[j];
        }
        __syncthreads();
    }

#pragma unroll
    for (int i = 0; i < 4; i++) {
        int o = o0 + 4 * ty + i;
        float bo = bias[o];
#pragma unroll
        for (int j = 0; j < 4; j++)
            out[((b * Ox) + o) * HWx + n0 + 4 * tx + j] = acc[i][j] + bo;
    }
}

extern "C" void kernel_launch(void* const* d_in, const int* in_sizes, int n_in,
                              void* d_out, int out_size, void* d_ws, size_t ws_size,
                              hipStream_t stream) {
    const float* x      = (const float*)d_in[0];
    const float* w_off  = (const float*)d_in[1];
    const float* b_off  = (const float*)d_in[2];
    const float* weight = (const float*)d_in[3];
    const float* bias   = (const float*)d_in[4];
    float* out = (float*)d_out;
    float* ws  = (float*)d_ws;

    float* tmp   = ws;
    float* w_t   = ws + 884736;
    float* stats = ws + 946944;
    float* agg   = ws + 947008;

    k_init<<<dim3((884736 + 255) / 256), 256, 0, stream>>>(b_off, tmp, 884736);
    k_wtr<<<dim3((NOFF * Cx * 9 + 255) / 256), 256, 0, stream>>>(w_off, w_t);
    k1_offconv<<<dim3(HWx / 256, Bx, 16), 256, 0, stream>>>(x, w_t, tmp);
    k2_softmax<<<dim3(Bx * Kx), 256, 0, stream>>>(tmp, stats);
    k3_sample<<<dim3(HWx / 256, Bx, 8), 256, 0, stream>>>(x, tmp, stats, agg);
    k4_gemm<<<dim3(HWx / 64, Ox / 64, Bx), 256, 0, stream>>>(agg, weight, bias, out);
}

// Round 4
// 454.765 us; speedup vs baseline: 1.1757x; 1.1757x over previous
//
#include <hip/hip_runtime.h>
#include <hip/hip_fp16.h>

#define Bx 2
#define Cx 256
#define Hx 128
#define Wx 128
#define HWx (Hx*Wx)     // 16384
#define Ox 256
#define Kx 9
#define NOFF 27         // 3*K offset-conv output channels

// ws layout (float offsets):
//   tmp   [0, 884736)            B*27*HW
//   w_t   [884736, 946944)       27*256*9 transposed to [c][oc][t]
//   stats [946944, 947008)       18*2 (max, 1/sum) padded
//   agg   [947008, 947008+8388608)

// init tmp with bias (conv accumulates on top via atomics)
__global__ void k_init(const float* __restrict__ b_off, float* __restrict__ p, int n) {
    int i = blockIdx.x * 256 + threadIdx.x;
    if (i < n) p[i] = b_off[(i / HWx) % NOFF];
}

__global__ void k_wtr(const float* __restrict__ w_off, float* __restrict__ w_t) {
    int i = blockIdx.x * 256 + threadIdx.x;
    if (i >= NOFF * Cx * 9) return;
    int oc = i / (Cx * 9);
    int r  = i % (Cx * 9);
    int c  = r / 9;
    int t  = r % 9;
    w_t[(c * NOFF + oc) * 9 + t] = w_off[i];
}

// 3x3 conv C=256 -> 27, pad 1. Thread per pixel.
// grid (8, 128, B): x = row-band (XCD-pinned: linear%8 == blockIdx.x),
// y = chunk(16 of 16ch) * 8 + tile-in-band(8), z = b.
__global__ __launch_bounds__(256) void k1_offconv(
        const float* __restrict__ x, const float* __restrict__ w_t,
        float* __restrict__ tmp) {
    int tid  = threadIdx.x;
    int band = blockIdx.x;            // 0..7
    int yy_  = blockIdx.y;
    int b    = blockIdx.z;
    int tileT = band * 8 + (yy_ & 7); // hw tile 0..63
    int cc    = yy_ >> 3;             // c-chunk 0..15
    int hw  = tileT * 256 + tid;
    int y   = hw >> 7;
    int xx  = hw & (Wx - 1);

    float acc[NOFF];
#pragma unroll
    for (int oc = 0; oc < NOFF; oc++) acc[oc] = 0.f;

    const float* xb = x + ((b * Cx) + cc * 16) * HWx;
    const float* wc = w_t + (cc * 16) * (NOFF * 9);

    for (int ci = 0; ci < 16; ci++) {
        float t[9];
#pragma unroll
        for (int dy = -1; dy <= 1; dy++) {
            int yy = y + dy;
            bool vy = (yy >= 0) & (yy < Hx);
            int cy = min(max(yy, 0), Hx - 1);
#pragma unroll
            for (int dx = -1; dx <= 1; dx++) {
                int xq = xx + dx;
                bool v = vy & (xq >= 0) & (xq < Wx);
                int cx = min(max(xq, 0), Wx - 1);
                float val = xb[cy * Wx + cx];
                t[(dy + 1) * 3 + (dx + 1)] = v ? val : 0.f;
            }
        }
#pragma unroll
        for (int oc = 0; oc < NOFF; oc++) {
            acc[oc] += wc[oc * 9 + 0] * t[0] + wc[oc * 9 + 1] * t[1] + wc[oc * 9 + 2] * t[2]
                     + wc[oc * 9 + 3] * t[3] + wc[oc * 9 + 4] * t[4] + wc[oc * 9 + 5] * t[5]
                     + wc[oc * 9 + 6] * t[6] + wc[oc * 9 + 7] * t[7] + wc[oc * 9 + 8] * t[8];
        }
        xb += HWx;
        wc += NOFF * 9;
    }
#pragma unroll
    for (int oc = 0; oc < NOFF; oc++)
        atomicAdd(&tmp[((b * NOFF + oc) * HWx) + hw], acc[oc]);
}

// Per-(b,k) spatial softmax stats over HW: stats[bk*2]=max, stats[bk*2+1]=1/sum(exp(v-max))
__global__ __launch_bounds__(256) void k2_softmax(
        const float* __restrict__ tmp, float* __restrict__ stats) {
    int bk = blockIdx.x;              // 0..17
    int b = bk / Kx, k = bk % Kx;
    const float* p = tmp + ((b * NOFF) + 2 * Kx + k) * HWx;
    __shared__ float red[256];
    int tid = threadIdx.x;
    float mx = -1e30f;
    for (int i = tid; i < HWx; i += 256) mx = fmaxf(mx, p[i]);
    red[tid] = mx; __syncthreads();
    for (int s = 128; s > 0; s >>= 1) {
        if (tid < s) red[tid] = fmaxf(red[tid], red[tid + s]);
        __syncthreads();
    }
    mx = red[0]; __syncthreads();
    float sm = 0.f;
    for (int i = tid; i < HWx; i += 256) sm += __expf(p[i] - mx);
    red[tid] = sm; __syncthreads();
    for (int s = 128; s > 0; s >>= 1) {
        if (tid < s) red[tid] += red[tid + s];
        __syncthreads();
    }
    if (tid == 0) { stats[bk * 2] = mx; stats[bk * 2 + 1] = 1.f / red[0]; }
}

// Bilinear sample * softmax mask, summed over k -> agg[b,c,h,w].
// grid (8, 128, B): x = row-band (XCD-pinned), y = chunk(16)*8 + tile(8), z = b.
// Coefficients packed: 18 half2 weights (x256 scale), 18 ushort2 byte-offsets.
// Inner loop interleaves 4 channels (independent accumulators, shared unpack).
__global__ __launch_bounds__(256) void k3_sample(
        const float* __restrict__ x, const float* __restrict__ tmp,
        const float* __restrict__ stats, float* __restrict__ agg) {
    int tid  = threadIdx.x;
    int band = blockIdx.x;
    int yy_  = blockIdx.y;
    int b    = blockIdx.z;
    int tileT = band * 8 + (yy_ & 7);
    int c0    = (yy_ >> 3) * 16;
    int hw  = tileT * 256 + tid;
    int y   = hw >> 7;
    int xx  = hw & (Wx - 1);

    unsigned int cwp[18];   // half2 packed weights (pre-scaled by 256)
    unsigned int cop[18];   // ushort2 packed byte offsets into the channel plane

#pragma unroll
    for (int k = 0; k < Kx; k++) {
        float dy = tmp[((b * NOFF) + 2 * k) * HWx + hw];
        float dx = tmp[((b * NOFF) + 2 * k + 1) * HWx + hw];
        float lg = tmp[((b * NOFF) + 2 * Kx + k) * HWx + hw];
        float m  = __expf(lg - stats[(b * Kx + k) * 2]) * stats[(b * Kx + k) * 2 + 1] * 256.f;
        float py = dy + (float)(k / 3 - 1 + y);
        float px = dx + (float)(k % 3 - 1 + xx);
        float fy = floorf(py), fx = floorf(px);
        int y0 = (int)fy, x0 = (int)fx;
        float ly = py - fy, lx = px - fx;
        float w00 = (1.f - ly) * (1.f - lx) * m;
        float w01 = (1.f - ly) * lx * m;
        float w10 = ly * (1.f - lx) * m;
        float w11 = ly * lx * m;
        int y1 = y0 + 1, x1 = x0 + 1;
        bool vy0 = (y0 >= 0) & (y0 < Hx), vy1 = (y1 >= 0) & (y1 < Hx);
        bool vx0 = (x0 >= 0) & (x0 < Wx), vx1 = (x1 >= 0) & (x1 < Wx);
        int cy0 = min(max(y0, 0), Hx - 1), cy1 = min(max(y1, 0), Hx - 1);
        int cx0 = min(max(x0, 0), Wx - 1), cx1 = min(max(x1, 0), Wx - 1);
        float a00 = (vy0 && vx0) ? w00 : 0.f;
        float a01 = (vy0 && vx1) ? w01 : 0.f;
        float a10 = (vy1 && vx0) ? w10 : 0.f;
        float a11 = (vy1 && vx1) ? w11 : 0.f;
        unsigned int o00 = (unsigned int)((cy0 * Wx + cx0) * 4);
        unsigned int o01 = (unsigned int)((cy0 * Wx + cx1) * 4);
        unsigned int o10 = (unsigned int)((cy1 * Wx + cx0) * 4);
        unsigned int o11 = (unsigned int)((cy1 * Wx + cx1) * 4);
        __half2 h0 = __halves2half2(__float2half_rn(a00), __float2half_rn(a01));
        __half2 h1 = __halves2half2(__float2half_rn(a10), __float2half_rn(a11));
        cwp[2 * k]     = *(unsigned int*)&h0;
        cwp[2 * k + 1] = *(unsigned int*)&h1;
        cop[2 * k]     = o00 | (o01 << 16);
        cop[2 * k + 1] = o10 | (o11 << 16);
    }

    const char* xb = (const char*)(x + ((b * Cx) + c0) * HWx);
    float* ab = agg + ((b * Cx) + c0) * HWx + hw;
#pragma unroll 1
    for (int cg = 0; cg < 4; cg++) {
        const char* p0 = xb;
        const char* p1 = xb + HWx * 4;
        const char* p2 = xb + HWx * 8;
        const char* p3 = xb + HWx * 12;
        float a0 = 0.f, a1 = 0.f, a2 = 0.f, a3 = 0.f;
#pragma unroll
        for (int i = 0; i < 18; i++) {
            unsigned int oo = cop[i];
            unsigned int ww = cwp[i];
            unsigned int off0 = oo & 0xFFFFu;
            unsigned int off1 = oo >> 16;
            float2 wf = __half22float2(*(const __half2*)&ww);
            a0 += wf.x * *(const float*)(p0 + off0);
            a1 += wf.x * *(const float*)(p1 + off0);
            a2 += wf.x * *(const float*)(p2 + off0);
            a3 += wf.x * *(const float*)(p3 + off0);
            a0 += wf.y * *(const float*)(p0 + off1);
            a1 += wf.y * *(const float*)(p1 + off1);
            a2 += wf.y * *(const float*)(p2 + off1);
            a3 += wf.y * *(const float*)(p3 + off1);
        }
        const float s = 1.f / 256.f;
        ab[0]        = a0 * s;
        ab[HWx]      = a1 * s;
        ab[HWx * 2]  = a2 * s;
        ab[HWx * 3]  = a3 * s;
        xb += HWx * 16;
        ab += HWx * 4;
    }
}

// out[b,o,hw] = bias[o] + sum_c weight[o,c] * agg[b,c,hw]
// Tile 64(o) x 64(hw), 256 threads, 4x4 per thread, K-step 16.
__global__ __launch_bounds__(256) void k4_gemm(
        const float* __restrict__ agg, const float* __restrict__ weight,
        const float* __restrict__ bias, float* __restrict__ out) {
    int b  = blockIdx.z;
    int o0 = blockIdx.y * 64;
    int n0 = blockIdx.x * 64;
    __shared__ float At[16][64];      // [k][hw]
    __shared__ float Wt[16][68];      // [k][o], padded for alignment/banks
    int tid = threadIdx.x;
    int tx = tid & 15;                // hw quad
    int ty = tid >> 4;                // o quad
    float acc[4][4];
#pragma unroll
    for (int i = 0; i < 4; i++)
#pragma unroll
        for (int j = 0; j < 4; j++) acc[i][j] = 0.f;

    for (int k0 = 0; k0 < Cx; k0 += 16) {
        {
            int kk = tid >> 6;        // 0..3
            int j  = tid & 63;
#pragma unroll
            for (int r = 0; r < 4; r++)
                At[kk + 4 * r][j] = agg[((b * Cx) + k0 + kk + 4 * r) * HWx + n0 + j];
        }
        {
            int ki = tid & 15;
            int oi = tid >> 4;        // 0..15
#pragma unroll
            for (int r = 0; r < 4; r++)
                Wt[ki][oi + 16 * r] = weight[(o0 + oi + 16 * r) * Cx + k0 + ki];
        }
        __syncthreads();
#pragma unroll
        for (int k = 0; k < 16; k++) {
            float a[4], w[4];
#pragma unroll
            for (int j = 0; j < 4; j++) a[j] = At[k][4 * tx + j];
#pragma unroll
            for (int i = 0; i < 4; i++) w[i] = Wt[k][4 * ty + i];
#pragma unroll
            for (int i = 0; i < 4; i++)
#pragma unroll
                for (int j = 0; j < 4; j++) acc[i][j] += w[i] * a[j];
        }
        __syncthreads();
    }

#pragma unroll
    for (int i = 0; i < 4; i++) {
        int o = o0 + 4 * ty + i;
        float bo = bias[o];
#pragma unroll
        for (int j = 0; j < 4; j++)
            out[((b * Ox) + o) * HWx + n0 + 4 * tx + j] = acc[i][j] + bo;
    }
}

extern "C" void kernel_launch(void* const* d_in, const int* in_sizes, int n_in,
                              void* d_out, int out_size, void* d_ws, size_t ws_size,
                              hipStream_t stream) {
    const float* x      = (const float*)d_in[0];
    const float* w_off  = (const float*)d_in[1];
    const float* b_off  = (const float*)d_in[2];
    const float* weight = (const float*)d_in[3];
    const float* bias   = (const float*)d_in[4];
    float* out = (float*)d_out;
    float* ws  = (float*)d_ws;

    float* tmp   = ws;
    float* w_t   = ws + 884736;
    float* stats = ws + 946944;
    float* agg   = ws + 947008;

    k_init<<<dim3((884736 + 255) / 256), 256, 0, stream>>>(b_off, tmp, 884736);
    k_wtr<<<dim3((NOFF * Cx * 9 + 255) / 256), 256, 0, stream>>>(w_off, w_t);
    k1_offconv<<<dim3(8, 128, Bx), 256, 0, stream>>>(x, w_t, tmp);
    k2_softmax<<<dim3(Bx * Kx), 256, 0, stream>>>(tmp, stats);
    k3_sample<<<dim3(8, 128, Bx), 256, 0, stream>>>(x, tmp, stats, agg);
    k4_gemm<<<dim3(HWx / 64, Ox / 64, Bx), 256, 0, stream>>>(agg, weight, bias, out);
}

// Round 5
// 322.587 us; speedup vs baseline: 1.6574x; 1.4097x over previous
//
#include <hip/hip_runtime.h>

#define Bx 2
#define Cx 256
#define Hx 128
#define Wx 128
#define HWx (Hx*Wx)     // 16384
#define Ox 256
#define Kx 9
#define NOFF 27         // 3*K offset-conv output channels

// ws layout (float offsets):
//   tmp   [0, 884736)            B*27*HW
//   w_t   [884736, 946944)       27*256*9 transposed to [c][oc][t]
//   stats [946944, 947008)       18*2 (max, 1/sum) padded
//   xts   [947008, 947008+8388608)   x transposed to [b][hw][c] (staging)
// k3 writes agg_t[b][hw][c] into the x input buffer (restored by harness).

// init tmp with bias (conv accumulates on top via atomics)
__global__ void k_init(const float* __restrict__ b_off, float* __restrict__ p, int n) {
    int i = blockIdx.x * 256 + threadIdx.x;
    if (i < n) p[i] = b_off[(i / HWx) % NOFF];
}

__global__ void k_wtr(const float* __restrict__ w_off, float* __restrict__ w_t) {
    int i = blockIdx.x * 256 + threadIdx.x;
    if (i >= NOFF * Cx * 9) return;
    int oc = i / (Cx * 9);
    int r  = i % (Cx * 9);
    int c  = r / 9;
    int t  = r % 9;
    w_t[(c * NOFF + oc) * 9 + t] = w_off[i];
}

// Transpose x[b][c][hw] -> xt[b][hw][c]. 64x64 tiles via LDS.
__global__ __launch_bounds__(256) void k_tr(
        const float* __restrict__ x, float* __restrict__ xt) {
    __shared__ float tl[64][65];
    int tid = threadIdx.x;
    int hw0 = blockIdx.x * 64;
    int c0  = blockIdx.y * 64;
    int b   = blockIdx.z;
#pragma unroll
    for (int r = 0; r < 4; r++) {
        int cl = r * 16 + (tid >> 4);
        int hl = (tid & 15) * 4;
        const float4 v = *(const float4*)&x[((size_t)(b * Cx + c0 + cl)) * HWx + hw0 + hl];
        tl[cl][hl + 0] = v.x; tl[cl][hl + 1] = v.y; tl[cl][hl + 2] = v.z; tl[cl][hl + 3] = v.w;
    }
    __syncthreads();
#pragma unroll
    for (int r = 0; r < 4; r++) {
        int hl = r * 16 + (tid >> 4);
        int cl = (tid & 15) * 4;
        float4 v;
        v.x = tl[cl + 0][hl]; v.y = tl[cl + 1][hl]; v.z = tl[cl + 2][hl]; v.w = tl[cl + 3][hl];
        *(float4*)&xt[((size_t)b * HWx + hw0 + hl) * Cx + c0 + cl] = v;
    }
}

// 3x3 conv C=256 -> 27, pad 1. Thread per pixel.
// grid (8, 128, B): x = row-band (XCD-pinned), y = chunk(16)*8 + tile(8), z = b.
__global__ __launch_bounds__(256) void k1_offconv(
        const float* __restrict__ x, const float* __restrict__ w_t,
        float* __restrict__ tmp) {
    int tid  = threadIdx.x;
    int band = blockIdx.x;            // 0..7
    int yy_  = blockIdx.y;
    int b    = blockIdx.z;
    int tileT = band * 8 + (yy_ & 7); // hw tile 0..63
    int cc    = yy_ >> 3;             // c-chunk 0..15
    int hw  = tileT * 256 + tid;
    int y   = hw >> 7;
    int xx  = hw & (Wx - 1);

    float acc[NOFF];
#pragma unroll
    for (int oc = 0; oc < NOFF; oc++) acc[oc] = 0.f;

    const float* xb = x + ((b * Cx) + cc * 16) * HWx;
    const float* wc = w_t + (cc * 16) * (NOFF * 9);

    for (int ci = 0; ci < 16; ci++) {
        float t[9];
#pragma unroll
        for (int dy = -1; dy <= 1; dy++) {
            int yy = y + dy;
            bool vy = (yy >= 0) & (yy < Hx);
            int cy = min(max(yy, 0), Hx - 1);
#pragma unroll
            for (int dx = -1; dx <= 1; dx++) {
                int xq = xx + dx;
                bool v = vy & (xq >= 0) & (xq < Wx);
                int cx = min(max(xq, 0), Wx - 1);
                float val = xb[cy * Wx + cx];
                t[(dy + 1) * 3 + (dx + 1)] = v ? val : 0.f;
            }
        }
#pragma unroll
        for (int oc = 0; oc < NOFF; oc++) {
            acc[oc] += wc[oc * 9 + 0] * t[0] + wc[oc * 9 + 1] * t[1] + wc[oc * 9 + 2] * t[2]
                     + wc[oc * 9 + 3] * t[3] + wc[oc * 9 + 4] * t[4] + wc[oc * 9 + 5] * t[5]
                     + wc[oc * 9 + 6] * t[6] + wc[oc * 9 + 7] * t[7] + wc[oc * 9 + 8] * t[8];
        }
        xb += HWx;
        wc += NOFF * 9;
    }
#pragma unroll
    for (int oc = 0; oc < NOFF; oc++)
        atomicAdd(&tmp[((b * NOFF + oc) * HWx) + hw], acc[oc]);
}

// Per-(b,k) spatial softmax stats over HW: stats[bk*2]=max, stats[bk*2+1]=1/sum(exp(v-max))
__global__ __launch_bounds__(256) void k2_softmax(
        const float* __restrict__ tmp, float* __restrict__ stats) {
    int bk = blockIdx.x;              // 0..17
    int b = bk / Kx, k = bk % Kx;
    const float* p = tmp + ((b * NOFF) + 2 * Kx + k) * HWx;
    __shared__ float red[256];
    int tid = threadIdx.x;
    float mx = -1e30f;
    for (int i = tid; i < HWx; i += 256) mx = fmaxf(mx, p[i]);
    red[tid] = mx; __syncthreads();
    for (int s = 128; s > 0; s >>= 1) {
        if (tid < s) red[tid] = fmaxf(red[tid], red[tid + s]);
        __syncthreads();
    }
    mx = red[0]; __syncthreads();
    float sm = 0.f;
    for (int i = tid; i < HWx; i += 256) sm += __expf(p[i] - mx);
    red[tid] = sm; __syncthreads();
    for (int s = 128; s > 0; s >>= 1) {
        if (tid < s) red[tid] += red[tid + s];
        __syncthreads();
    }
    if (tid == 0) { stats[bk * 2] = mx; stats[bk * 2 + 1] = 1.f / red[0]; }
}

// Bilinear sample * softmax mask, summed over k.
// x_t[b][hw][c] -> agg_t[b][hw][c].  Wave = pixel, lanes = 64 x float4 channels.
// grid (1024, B): blockIdx.x: band = &7 (XCD), sub = >>3; 16 px per block.
__global__ __launch_bounds__(256) void k3_sample(
        const float* __restrict__ x_t, const float* __restrict__ tmp,
        const float* __restrict__ stats, float* __restrict__ agg_t) {
    __shared__ float lw[16][36];
    __shared__ int   lo[16][36];
    int tid  = threadIdx.x;
    int band = blockIdx.x & 7;
    int sub  = blockIdx.x >> 3;
    int b    = blockIdx.y;
    int px0  = (band * 128 + sub) * 16;

    if (tid < 144) {
        int px = tid / 9, k = tid - px * 9;
        int hw = px0 + px;
        int y  = hw >> 7;
        int xx = hw & (Wx - 1);
        float dy = tmp[((b * NOFF) + 2 * k) * HWx + hw];
        float dx = tmp[((b * NOFF) + 2 * k + 1) * HWx + hw];
        float lg = tmp[((b * NOFF) + 2 * Kx + k) * HWx + hw];
        float m  = __expf(lg - stats[(b * Kx + k) * 2]) * stats[(b * Kx + k) * 2 + 1];
        float py = dy + (float)(k / 3 - 1 + y);
        float px_ = dx + (float)(k % 3 - 1 + xx);
        float fy = floorf(py), fx = floorf(px_);
        int y0 = (int)fy, x0 = (int)fx;
        float ly = py - fy, lx = px_ - fx;
        float w00 = (1.f - ly) * (1.f - lx) * m;
        float w01 = (1.f - ly) * lx * m;
        float w10 = ly * (1.f - lx) * m;
        float w11 = ly * lx * m;
        int y1 = y0 + 1, x1 = x0 + 1;
        bool vy0 = (y0 >= 0) & (y0 < Hx), vy1 = (y1 >= 0) & (y1 < Hx);
        bool vx0 = (x0 >= 0) & (x0 < Wx), vx1 = (x1 >= 0) & (x1 < Wx);
        int cy0 = min(max(y0, 0), Hx - 1), cy1 = min(max(y1, 0), Hx - 1);
        int cx0 = min(max(x0, 0), Wx - 1), cx1 = min(max(x1, 0), Wx - 1);
        lw[px][4 * k + 0] = (vy0 && vx0) ? w00 : 0.f;  lo[px][4 * k + 0] = cy0 * Wx + cx0;
        lw[px][4 * k + 1] = (vy0 && vx1) ? w01 : 0.f;  lo[px][4 * k + 1] = cy0 * Wx + cx1;
        lw[px][4 * k + 2] = (vy1 && vx0) ? w10 : 0.f;  lo[px][4 * k + 2] = cy1 * Wx + cx0;
        lw[px][4 * k + 3] = (vy1 && vx1) ? w11 : 0.f;  lo[px][4 * k + 3] = cy1 * Wx + cx1;
    }
    __syncthreads();

    int wave = tid >> 6;
    int lane = tid & 63;
    const float* xb = x_t + (size_t)b * HWx * Cx + lane * 4;
#pragma unroll 1
    for (int t = 0; t < 4; t++) {
        int px = wave * 4 + t;
        float a0 = 0.f, a1 = 0.f, a2 = 0.f, a3 = 0.f;
#pragma unroll
        for (int j = 0; j < 36; j++) {
            float w  = lw[px][j];
            int  off = lo[px][j];
            const float4 v = *(const float4*)(xb + (size_t)off * Cx);
            a0 += w * v.x; a1 += w * v.y; a2 += w * v.z; a3 += w * v.w;
        }
        float4 r; r.x = a0; r.y = a1; r.z = a2; r.w = a3;
        *(float4*)(agg_t + ((size_t)b * HWx + px0 + px) * Cx + lane * 4) = r;
    }
}

// out[b,o,hw] = bias[o] + sum_c weight[o,c] * agg_t[b,hw,c]
// Tile 64(o) x 64(hw), 256 threads, 4x4 per thread, K-step 16.
__global__ __launch_bounds__(256) void k4_gemm(
        const float* __restrict__ agg_t, const float* __restrict__ weight,
        const float* __restrict__ bias, float* __restrict__ out) {
    int b  = blockIdx.z;
    int o0 = blockIdx.y * 64;
    int n0 = blockIdx.x * 64;
    __shared__ float Bs[16][68];      // [c][hw]
    __shared__ float Wt[16][68];      // [c][o]
    int tid = threadIdx.x;
    int tx = tid & 15;                // hw quad
    int ty = tid >> 4;                // o quad
    float acc[4][4];
#pragma unroll
    for (int i = 0; i < 4; i++)
#pragma unroll
        for (int j = 0; j < 4; j++) acc[i][j] = 0.f;

    for (int k0 = 0; k0 < Cx; k0 += 16) {
        {
            int hw_l = tid >> 2;
            int cs   = (tid & 3) * 4;
            const float4 v = *(const float4*)&agg_t[((size_t)b * HWx + n0 + hw_l) * Cx + k0 + cs];
            Bs[cs + 0][hw_l] = v.x; Bs[cs + 1][hw_l] = v.y;
            Bs[cs + 2][hw_l] = v.z; Bs[cs + 3][hw_l] = v.w;
        }
        {
            int ki = tid & 15;
            int oi = tid >> 4;        // 0..15
#pragma unroll
            for (int r = 0; r < 4; r++)
                Wt[ki][oi + 16 * r] = weight[(o0 + oi + 16 * r) * Cx + k0 + ki];
        }
        __syncthreads();
#pragma unroll
        for (int k = 0; k < 16; k++) {
            float a[4], w[4];
#pragma unroll
            for (int j = 0; j < 4; j++) a[j] = Bs[k][4 * tx + j];
#pragma unroll
            for (int i = 0; i < 4; i++) w[i] = Wt[k][4 * ty + i];
#pragma unroll
            for (int i = 0; i < 4; i++)
#pragma unroll
                for (int j = 0; j < 4; j++) acc[i][j] += w[i] * a[j];
        }
        __syncthreads();
    }

#pragma unroll
    for (int i = 0; i < 4; i++) {
        int o = o0 + 4 * ty + i;
        float bo = bias[o];
#pragma unroll
        for (int j = 0; j < 4; j++)
            out[((b * Ox) + o) * HWx + n0 + 4 * tx + j] = acc[i][j] + bo;
    }
}

extern "C" void kernel_launch(void* const* d_in, const int* in_sizes, int n_in,
                              void* d_out, int out_size, void* d_ws, size_t ws_size,
                              hipStream_t stream) {
    const float* x      = (const float*)d_in[0];
    float*       xbuf   = (float*)d_in[0];     // reused as agg_t after last read of x
    const float* w_off  = (const float*)d_in[1];
    const float* b_off  = (const float*)d_in[2];
    const float* weight = (const float*)d_in[3];
    const float* bias   = (const float*)d_in[4];
    float* out = (float*)d_out;
    float* ws  = (float*)d_ws;

    float* tmp   = ws;
    float* w_t   = ws + 884736;
    float* stats = ws + 946944;
    float* xts   = ws + 947008;       // x transposed [b][hw][c]

    k_init<<<dim3((884736 + 255) / 256), 256, 0, stream>>>(b_off, tmp, 884736);
    k_wtr<<<dim3((NOFF * Cx * 9 + 255) / 256), 256, 0, stream>>>(w_off, w_t);
    k1_offconv<<<dim3(8, 128, Bx), 256, 0, stream>>>(x, w_t, tmp);
    k2_softmax<<<dim3(Bx * Kx), 256, 0, stream>>>(tmp, stats);
    k_tr<<<dim3(HWx / 64, Cx / 64, Bx), 256, 0, stream>>>(x, xts);
    // x fully consumed; k3 overwrites the x buffer with agg_t[b][hw][c]
    k3_sample<<<dim3(1024, Bx), 256, 0, stream>>>(xts, tmp, stats, xbuf);
    k4_gemm<<<dim3(HWx / 64, Ox / 64, Bx), 256, 0, stream>>>(xbuf, weight, bias, out);
}

// Round 7
// 281.588 us; speedup vs baseline: 1.8987x; 1.1456x over previous
//
#include <hip/hip_runtime.h>

#define Bx 2
#define Cx 256
#define Hx 128
#define Wx 128
#define HWx (Hx*Wx)     // 16384
#define Ox 256
#define Kx 9
#define NOFF 27         // 3*K offset-conv output channels
#define KK 2304         // 9 taps * 256 channels

typedef __attribute__((ext_vector_type(8))) short bf16x8;
typedef __attribute__((ext_vector_type(4))) float f32x4;

// ws layout (float offsets):
//   tmp_t [0, 1048576)             B*HW*32  (27 used, pad 32; [b][hw][oc])
//   stats [1048576, 1048640)       18*2 (max, 1/sum) padded
//   wbq   [1048640, 1085504)       bf16 W[32][2304], k = tap*256+c  (73728 ushorts)
//   xtb   [1085504, ...)           bf16 x transposed [b][hw][c] (16.8 MB)
// k3 writes agg_t[b][hw][c] (fp32) into the x input buffer (restored by harness).

__device__ __forceinline__ unsigned short f2bf(float f) {
    unsigned int u = __float_as_uint(f);
    u = u + 0x7FFFu + ((u >> 16) & 1u);
    return (unsigned short)(u >> 16);
}

// tmp_t[b][hw][oc] = b_off[oc] (oc<27) else 0; conv atomically accumulates on top.
__global__ void k_init(const float* __restrict__ b_off, float* __restrict__ p) {
    int i = blockIdx.x * 256 + threadIdx.x;   // over B*HW*32
    int oc = i & 31;
    p[i] = (oc < NOFF) ? b_off[oc] : 0.f;
}

// Wb[oc][tap*256+c] bf16 (rows 27..31 zero) from w_off[oc][c][tap]
__global__ void k_wtr(const float* __restrict__ w_off, unsigned short* __restrict__ wb) {
    int i = blockIdx.x * 256 + threadIdx.x;
    if (i >= 32 * KK) return;
    int oc = i / KK;
    int k  = i - oc * KK;
    int tap = k >> 8;
    int c   = k & 255;
    float v = (oc < NOFF) ? w_off[(oc * Cx + c) * 9 + tap] : 0.f;
    wb[i] = f2bf(v);
}

// Transpose+convert x[b][c][hw] -> xtb[b][hw][c] bf16. 64x64 tiles via LDS.
__global__ __launch_bounds__(256) void k_tr(
        const float* __restrict__ x, unsigned short* __restrict__ xtb) {
    __shared__ float tl[64][65];
    int tid = threadIdx.x;
    int hw0 = blockIdx.x * 64;
    int c0  = blockIdx.y * 64;
    int b   = blockIdx.z;
#pragma unroll
    for (int r = 0; r < 4; r++) {
        int cl = r * 16 + (tid >> 4);
        int hl = (tid & 15) * 4;
        const float4 v = *(const float4*)&x[((size_t)(b * Cx + c0 + cl)) * HWx + hw0 + hl];
        tl[cl][hl + 0] = v.x; tl[cl][hl + 1] = v.y; tl[cl][hl + 2] = v.z; tl[cl][hl + 3] = v.w;
    }
    __syncthreads();
#pragma unroll
    for (int r = 0; r < 4; r++) {
        int hl = r * 16 + (tid >> 4);
        int cl = (tid & 15) * 4;
        ushort4 o;
        o.x = f2bf(tl[cl + 0][hl]); o.y = f2bf(tl[cl + 1][hl]);
        o.z = f2bf(tl[cl + 2][hl]); o.w = f2bf(tl[cl + 3][hl]);
        *(ushort4*)&xtb[((size_t)b * HWx + hw0 + hl) * Cx + c0 + cl] = o;
    }
}

// Offset conv as MFMA GEMM: tmp_t[px][oc] += sum_c W[oc][tap,c] * x[c][px shifted by tap]
// grid (128, 9, B): x = row (band-decoded for XCD locality), y = tap, z = b.
// Block 256 = 4 waves; M=128 px (1 image row), N=32 oc, K=256 ch (this tap).
__global__ __launch_bounds__(256) void k1_mfma(
        const unsigned short* __restrict__ xtb, const unsigned short* __restrict__ wb,
        float* __restrict__ tmp_t) {
    int band = blockIdx.x & 7;
    int sub  = blockIdx.x >> 3;
    int y    = band * 16 + sub;       // output row
    int tap  = blockIdx.y;
    int b    = blockIdx.z;
    int dy = tap / 3 - 1, dx = tap % 3 - 1;
    int yy = y + dy;
    if (yy < 0 || yy >= Hx) return;   // whole-row contribution is zero (block-uniform)

    __shared__ unsigned short As[128][136];   // [px][c-local], pad 136 (272B rows, 16B-aligned)
    int tid  = threadIdx.x;
    int wave = tid >> 6, lane = tid & 63;
    int quad = lane >> 4, col = lane & 15;

    f32x4 acc[2][2] = {};

    const unsigned short* xrow = xtb + ((size_t)(b * HWx) + (size_t)yy * Wx) * Cx;
    int px = tid >> 1;                // 0..127 (staging role)
    int h  = tid & 1;
    int sx = px + dx;
    bool vx = (sx >= 0) & (sx < Wx);

#pragma unroll 1
    for (int ph = 0; ph < 2; ph++) {
        __syncthreads();
        {   // stage channels [ph*128, ph*128+128) for all 128 px: 64 ch (=8 uint4) per (px,h)
            const unsigned short* src = xrow + (size_t)sx * Cx + ph * 128 + h * 64;
#pragma unroll
            for (int j = 0; j < 8; j++) {
                uint4 v = vx ? *(const uint4*)(src + j * 8) : make_uint4(0, 0, 0, 0);
                *(uint4*)&As[px][h * 64 + j * 8] = v;
            }
        }
        __syncthreads();
#pragma unroll
        for (int s = 0; s < 4; s++) {
            int kl = s * 32 + quad * 8;               // phase-local k
            int kg = tap * 256 + ph * 128 + kl;       // global k into wb rows
            bf16x8 a0 = *(const bf16x8*)&As[wave * 32 + col][kl];
            bf16x8 a1 = *(const bf16x8*)&As[wave * 32 + 16 + col][kl];
            bf16x8 b0 = *(const bf16x8*)(wb + (size_t)col * KK + kg);
            bf16x8 b1 = *(const bf16x8*)(wb + (size_t)(16 + col) * KK + kg);
            acc[0][0] = __builtin_amdgcn_mfma_f32_16x16x32_bf16(a0, b0, acc[0][0], 0, 0, 0);
            acc[0][1] = __builtin_amdgcn_mfma_f32_16x16x32_bf16(a0, b1, acc[0][1], 0, 0, 0);
            acc[1][0] = __builtin_amdgcn_mfma_f32_16x16x32_bf16(a1, b0, acc[1][0], 0, 0, 0);
            acc[1][1] = __builtin_amdgcn_mfma_f32_16x16x32_bf16(a1, b1, acc[1][1], 0, 0, 0);
        }
    }

    float* orow = tmp_t + ((size_t)(b * HWx) + (size_t)y * Wx) * 32;
#pragma unroll
    for (int mt = 0; mt < 2; mt++)
#pragma unroll
        for (int nt = 0; nt < 2; nt++)
#pragma unroll
            for (int r = 0; r < 4; r++) {
                int pxd = wave * 32 + mt * 16 + quad * 4 + r;
                int oc  = nt * 16 + col;
                atomicAdd(&orow[(size_t)pxd * 32 + oc], acc[mt][nt][r]);
            }
}

// Per-(b,k) spatial softmax stats over HW (tmp_t layout [hw][32], logits at 18+k)
__global__ __launch_bounds__(256) void k2_softmax(
        const float* __restrict__ tmp_t, float* __restrict__ stats) {
    int bk = blockIdx.x;              // 0..17
    int b = bk / Kx, k = bk % Kx;
    const float* p = tmp_t + (size_t)b * HWx * 32 + 18 + k;
    __shared__ float red[256];
    int tid = threadIdx.x;
    float mx = -1e30f;
    for (int i = tid; i < HWx; i += 256) mx = fmaxf(mx, p[(size_t)i * 32]);
    red[tid] = mx; __syncthreads();
    for (int s = 128; s > 0; s >>= 1) {
        if (tid < s) red[tid] = fmaxf(red[tid], red[tid + s]);
        __syncthreads();
    }
    mx = red[0]; __syncthreads();
    float sm = 0.f;
    for (int i = tid; i < HWx; i += 256) sm += __expf(p[(size_t)i * 32] - mx);
    red[tid] = sm; __syncthreads();
    for (int s = 128; s > 0; s >>= 1) {
        if (tid < s) red[tid] += red[tid + s];
        __syncthreads();
    }
    if (tid == 0) { stats[bk * 2] = mx; stats[bk * 2 + 1] = 1.f / red[0]; }
}

// Bilinear sample * softmax mask, summed over k.
// xtb[b][hw][c] (bf16) -> agg_t[b][hw][c] (fp32). Wave = pixel, lanes = 64 x 4 channels.
// grid (1024, B): band = &7 (XCD), sub = >>3; 16 px per block.
__global__ __launch_bounds__(256) void k3_sample(
        const unsigned short* __restrict__ xtb, const float* __restrict__ tmp_t,
        const float* __restrict__ stats, float* __restrict__ agg_t) {
    __shared__ float lw[16][36];
    __shared__ int   lo[16][36];
    int tid  = threadIdx.x;
    int band = blockIdx.x & 7;
    int sub  = blockIdx.x >> 3;
    int b    = blockIdx.y;
    int px0  = (band * 128 + sub) * 16;

    if (tid < 144) {
        int px = tid / 9, k = tid - px * 9;
        int hw = px0 + px;
        int y  = hw >> 7;
        int xx = hw & (Wx - 1);
        const float* trow = tmp_t + ((size_t)b * HWx + hw) * 32;
        float dy = trow[2 * k];
        float dx = trow[2 * k + 1];
        float lg = trow[18 + k];
        float m  = __expf(lg - stats[(b * Kx + k) * 2]) * stats[(b * Kx + k) * 2 + 1];
        float py = dy + (float)(k / 3 - 1 + y);
        float px_ = dx + (float)(k % 3 - 1 + xx);
        float fy = floorf(py), fx = floorf(px_);
        int y0 = (int)fy, x0 = (int)fx;
        float ly = py - fy, lx = px_ - fx;
        float w00 = (1.f - ly) * (1.f - lx) * m;
        float w01 = (1.f - ly) * lx * m;
        float w10 = ly * (1.f - lx) * m;
        float w11 = ly * lx * m;
        int y1 = y0 + 1, x1 = x0 + 1;
        bool vy0 = (y0 >= 0) & (y0 < Hx), vy1 = (y1 >= 0) & (y1 < Hx);
        bool vx0 = (x0 >= 0) & (x0 < Wx), vx1 = (x1 >= 0) & (x1 < Wx);
        int cy0 = min(max(y0, 0), Hx - 1), cy1 = min(max(y1, 0), Hx - 1);
        int cx0 = min(max(x0, 0), Wx - 1), cx1 = min(max(x1, 0), Wx - 1);
        lw[px][4 * k + 0] = (vy0 && vx0) ? w00 : 0.f;  lo[px][4 * k + 0] = cy0 * Wx + cx0;
        lw[px][4 * k + 1] = (vy0 && vx1) ? w01 : 0.f;  lo[px][4 * k + 1] = cy0 * Wx + cx1;
        lw[px][4 * k + 2] = (vy1 && vx0) ? w10 : 0.f;  lo[px][4 * k + 2] = cy1 * Wx + cx0;
        lw[px][4 * k + 3] = (vy1 && vx1) ? w11 : 0.f;  lo[px][4 * k + 3] = cy1 * Wx + cx1;
    }
    __syncthreads();

    int wave = tid >> 6;
    int lane = tid & 63;
    const unsigned short* xb = xtb + (size_t)b * HWx * Cx + lane * 4;
#pragma unroll 1
    for (int t = 0; t < 4; t++) {
        int px = wave * 4 + t;
        float a0 = 0.f, a1 = 0.f, a2 = 0.f, a3 = 0.f;
#pragma unroll
        for (int j = 0; j < 36; j++) {
            float w  = lw[px][j];
            int  off = lo[px][j];
            uint2 v = *(const uint2*)(xb + (size_t)off * Cx);
            float c0 = __uint_as_float(v.x << 16);
            float c1 = __uint_as_float(v.x & 0xFFFF0000u);
            float c2 = __uint_as_float(v.y << 16);
            float c3 = __uint_as_float(v.y & 0xFFFF0000u);
            a0 += w * c0; a1 += w * c1; a2 += w * c2; a3 += w * c3;
        }
        float4 r; r.x = a0; r.y = a1; r.z = a2; r.w = a3;
        *(float4*)(agg_t + ((size_t)b * HWx + px0 + px) * Cx + lane * 4) = r;
    }
}

// out[b,o,hw] = bias[o] + sum_c weight[o,c] * agg_t[b,hw,c]
// Tile 64(o) x 64(hw), 256 threads, 4x4 per thread, K-step 16.
__global__ __launch_bounds__(256) void k4_gemm(
        const float* __restrict__ agg_t, const float* __restrict__ weight,
        const float* __restrict__ bias, float* __restrict__ out) {
    int b  = blockIdx.z;
    int o0 = blockIdx.y * 64;
    int n0 = blockIdx.x * 64;
    __shared__ float Bs[16][68];      // [c][hw]
    __shared__ float Wt[16][68];      // [c][o]
    int tid = threadIdx.x;
    int tx = tid & 15;                // hw quad
    int ty = tid >> 4;                // o quad
    float acc[4][4];
#pragma unroll
    for (int i = 0; i < 4; i++)
#pragma unroll
        for (int j = 0; j < 4; j++) acc[i][j] = 0.f;

    for (int k0 = 0; k0 < Cx; k0 += 16) {
        {
            int hw_l = tid >> 2;
            int cs   = (tid & 3) * 4;
            const float4 v = *(const float4*)&agg_t[((size_t)b * HWx + n0 + hw_l) * Cx + k0 + cs];
            Bs[cs + 0][hw_l] = v.x; Bs[cs + 1][hw_l] = v.y;
            Bs[cs + 2][hw_l] = v.z; Bs[cs + 3][hw_l] = v.w;
        }
        {
            int ki = tid & 15;
            int oi = tid >> 4;        // 0..15
#pragma unroll
            for (int r = 0; r < 4; r++)
                Wt[ki][oi + 16 * r] = weight[(o0 + oi + 16 * r) * Cx + k0 + ki];
        }
        __syncthreads();
#pragma unroll
        for (int k = 0; k < 16; k++) {
            float a[4], w[4];
#pragma unroll
            for (int j = 0; j < 4; j++) a[j] = Bs[k][4 * tx + j];
#pragma unroll
            for (int i = 0; i < 4; i++) w[i] = Wt[k][4 * ty + i];
#pragma unroll
            for (int i = 0; i < 4; i++)
#pragma unroll
                for (int j = 0; j < 4; j++) acc[i][j] += w[i] * a[j];
        }
        __syncthreads();
    }

#pragma unroll
    for (int i = 0; i < 4; i++) {
        int o = o0 + 4 * ty + i;
        float bo = bias[o];
#pragma unroll
        for (int j = 0; j < 4; j++)
            out[((b * Ox) + o) * HWx + n0 + 4 * tx + j] = acc[i][j] + bo;
    }
}

extern "C" void kernel_launch(void* const* d_in, const int* in_sizes, int n_in,
                              void* d_out, int out_size, void* d_ws, size_t ws_size,
                              hipStream_t stream) {
    const float* x      = (const float*)d_in[0];
    float*       xbuf   = (float*)d_in[0];     // reused as agg_t after last read of x
    const float* w_off  = (const float*)d_in[1];
    const float* b_off  = (const float*)d_in[2];
    const float* weight = (const float*)d_in[3];
    const float* bias   = (const float*)d_in[4];
    float* out = (float*)d_out;
    float* ws  = (float*)d_ws;

    float*          tmp_t = ws;
    float*          stats = ws + 1048576;
    unsigned short* wbq   = (unsigned short*)(ws + 1048640);
    unsigned short* xtb   = (unsigned short*)(ws + 1085504);

    k_init<<<dim3(Bx * HWx * 32 / 256), 256, 0, stream>>>(b_off, tmp_t);
    k_wtr<<<dim3((32 * KK + 255) / 256), 256, 0, stream>>>(w_off, wbq);
    k_tr<<<dim3(HWx / 64, Cx / 64, Bx), 256, 0, stream>>>(x, xtb);
    k1_mfma<<<dim3(128, 9, Bx), 256, 0, stream>>>(xtb, wbq, tmp_t);
    k2_softmax<<<dim3(Bx * Kx), 256, 0, stream>>>(tmp_t, stats);
    // x fully consumed (k_tr); k3 overwrites the x buffer with agg_t[b][hw][c]
    k3_sample<<<dim3(1024, Bx), 256, 0, stream>>>(xtb, tmp_t, stats, xbuf);
    k4_gemm<<<dim3(HWx / 64, Ox / 64, Bx), 256, 0, stream>>>(xbuf, weight, bias, out);
}

// Round 8
// 241.631 us; speedup vs baseline: 2.2127x; 1.1654x over previous
//
#include <hip/hip_runtime.h>

#define Bx 2
#define Cx 256
#define Hx 128
#define Wx 128
#define HWx (Hx*Wx)     // 16384
#define Ox 256
#define Kx 9
#define NOFF 27         // 3*K offset-conv output channels
#define KK 2304         // 9 taps * 256 channels

typedef __attribute__((ext_vector_type(8))) short bf16x8;
typedef __attribute__((ext_vector_type(4))) float f32x4;

// ws layout (float offsets):
//   tmp_t [0, 1048576)             B*HW*32  (27 used, pad 32; [b][hw][oc])
//   stats [1048576, 1048640)       18*2 (max, 1/sum) padded
//   wbq   [1048640, 1085504)       bf16 W[32][2304], k = tap*256+c
//   xtb   [1085504, 5279808)       bf16 x transposed [b][hw][c] (16.8 MB)
//   wq    [5279808, 5312576)       bf16 weight [o][c] (128 KB)
// k3 writes agg_t[b][hw][c] (bf16) into the x input buffer (restored by harness).

__device__ __forceinline__ unsigned short f2bf(float f) {
    unsigned int u = __float_as_uint(f);
    u = u + 0x7FFFu + ((u >> 16) & 1u);
    return (unsigned short)(u >> 16);
}

// tmp_t[b][hw][oc] = b_off[oc] (oc<27) else 0; conv atomically accumulates on top.
__global__ void k_init(const float* __restrict__ b_off, float* __restrict__ p) {
    int i = blockIdx.x * 256 + threadIdx.x;   // over B*HW*32
    int oc = i & 31;
    p[i] = (oc < NOFF) ? b_off[oc] : 0.f;
}

// Wb[oc][tap*256+c] bf16 (rows 27..31 zero) from w_off[oc][c][tap]
__global__ void k_wtr(const float* __restrict__ w_off, unsigned short* __restrict__ wb) {
    int i = blockIdx.x * 256 + threadIdx.x;
    if (i >= 32 * KK) return;
    int oc = i / KK;
    int k  = i - oc * KK;
    int tap = k >> 8;
    int c   = k & 255;
    float v = (oc < NOFF) ? w_off[(oc * Cx + c) * 9 + tap] : 0.f;
    wb[i] = f2bf(v);
}

// wq[o][c] bf16 from weight[o][c] fp32
__global__ void k_wq(const float* __restrict__ weight, unsigned short* __restrict__ wq) {
    int i = blockIdx.x * 256 + threadIdx.x;   // over 65536
    wq[i] = f2bf(weight[i]);
}

// Transpose+convert x[b][c][hw] -> xtb[b][hw][c] bf16. 64x64 tiles via LDS.
__global__ __launch_bounds__(256) void k_tr(
        const float* __restrict__ x, unsigned short* __restrict__ xtb) {
    __shared__ float tl[64][65];
    int tid = threadIdx.x;
    int hw0 = blockIdx.x * 64;
    int c0  = blockIdx.y * 64;
    int b   = blockIdx.z;
#pragma unroll
    for (int r = 0; r < 4; r++) {
        int cl = r * 16 + (tid >> 4);
        int hl = (tid & 15) * 4;
        const float4 v = *(const float4*)&x[((size_t)(b * Cx + c0 + cl)) * HWx + hw0 + hl];
        tl[cl][hl + 0] = v.x; tl[cl][hl + 1] = v.y; tl[cl][hl + 2] = v.z; tl[cl][hl + 3] = v.w;
    }
    __syncthreads();
#pragma unroll
    for (int r = 0; r < 4; r++) {
        int hl = r * 16 + (tid >> 4);
        int cl = (tid & 15) * 4;
        ushort4 o;
        o.x = f2bf(tl[cl + 0][hl]); o.y = f2bf(tl[cl + 1][hl]);
        o.z = f2bf(tl[cl + 2][hl]); o.w = f2bf(tl[cl + 3][hl]);
        *(ushort4*)&xtb[((size_t)b * HWx + hw0 + hl) * Cx + c0 + cl] = o;
    }
}

// Offset conv as MFMA GEMM: tmp_t[px][oc] += sum_c W[oc][tap,c] * x[c][px shifted by tap]
// grid (128, 9, B): x = row (band-decoded for XCD locality), y = tap, z = b.
__global__ __launch_bounds__(256) void k1_mfma(
        const unsigned short* __restrict__ xtb, const unsigned short* __restrict__ wb,
        float* __restrict__ tmp_t) {
    int band = blockIdx.x & 7;
    int sub  = blockIdx.x >> 3;
    int y    = band * 16 + sub;       // output row
    int tap  = blockIdx.y;
    int b    = blockIdx.z;
    int dy = tap / 3 - 1, dx = tap % 3 - 1;
    int yy = y + dy;
    if (yy < 0 || yy >= Hx) return;   // whole-row contribution is zero (block-uniform)

    __shared__ unsigned short As[128][136];
    int tid  = threadIdx.x;
    int wave = tid >> 6, lane = tid & 63;
    int quad = lane >> 4, col = lane & 15;

    f32x4 acc[2][2] = {};

    const unsigned short* xrow = xtb + ((size_t)(b * HWx) + (size_t)yy * Wx) * Cx;
    int px = tid >> 1;
    int h  = tid & 1;
    int sx = px + dx;
    bool vx = (sx >= 0) & (sx < Wx);

#pragma unroll 1
    for (int ph = 0; ph < 2; ph++) {
        __syncthreads();
        {
            const unsigned short* src = xrow + (size_t)sx * Cx + ph * 128 + h * 64;
#pragma unroll
            for (int j = 0; j < 8; j++) {
                uint4 v = vx ? *(const uint4*)(src + j * 8) : make_uint4(0, 0, 0, 0);
                *(uint4*)&As[px][h * 64 + j * 8] = v;
            }
        }
        __syncthreads();
#pragma unroll
        for (int s = 0; s < 4; s++) {
            int kl = s * 32 + quad * 8;
            int kg = tap * 256 + ph * 128 + kl;
            bf16x8 a0 = *(const bf16x8*)&As[wave * 32 + col][kl];
            bf16x8 a1 = *(const bf16x8*)&As[wave * 32 + 16 + col][kl];
            bf16x8 b0 = *(const bf16x8*)(wb + (size_t)col * KK + kg);
            bf16x8 b1 = *(const bf16x8*)(wb + (size_t)(16 + col) * KK + kg);
            acc[0][0] = __builtin_amdgcn_mfma_f32_16x16x32_bf16(a0, b0, acc[0][0], 0, 0, 0);
            acc[0][1] = __builtin_amdgcn_mfma_f32_16x16x32_bf16(a0, b1, acc[0][1], 0, 0, 0);
            acc[1][0] = __builtin_amdgcn_mfma_f32_16x16x32_bf16(a1, b0, acc[1][0], 0, 0, 0);
            acc[1][1] = __builtin_amdgcn_mfma_f32_16x16x32_bf16(a1, b1, acc[1][1], 0, 0, 0);
        }
    }

    float* orow = tmp_t + ((size_t)(b * HWx) + (size_t)y * Wx) * 32;
#pragma unroll
    for (int mt = 0; mt < 2; mt++)
#pragma unroll
        for (int nt = 0; nt < 2; nt++)
#pragma unroll
            for (int r = 0; r < 4; r++) {
                int pxd = wave * 32 + mt * 16 + quad * 4 + r;
                int oc  = nt * 16 + col;
                atomicAdd(&orow[(size_t)pxd * 32 + oc], acc[mt][nt][r]);
            }
}

// Per-(b,k) spatial softmax stats over HW (tmp_t layout [hw][32], logits at 18+k)
__global__ __launch_bounds__(256) void k2_softmax(
        const float* __restrict__ tmp_t, float* __restrict__ stats) {
    int bk = blockIdx.x;              // 0..17
    int b = bk / Kx, k = bk % Kx;
    const float* p = tmp_t + (size_t)b * HWx * 32 + 18 + k;
    __shared__ float red[256];
    int tid = threadIdx.x;
    float mx = -1e30f;
    for (int i = tid; i < HWx; i += 256) mx = fmaxf(mx, p[(size_t)i * 32]);
    red[tid] = mx; __syncthreads();
    for (int s = 128; s > 0; s >>= 1) {
        if (tid < s) red[tid] = fmaxf(red[tid], red[tid + s]);
        __syncthreads();
    }
    mx = red[0]; __syncthreads();
    float sm = 0.f;
    for (int i = tid; i < HWx; i += 256) sm += __expf(p[(size_t)i * 32] - mx);
    red[tid] = sm; __syncthreads();
    for (int s = 128; s > 0; s >>= 1) {
        if (tid < s) red[tid] += red[tid + s];
        __syncthreads();
    }
    if (tid == 0) { stats[bk * 2] = mx; stats[bk * 2 + 1] = 1.f / red[0]; }
}

// Bilinear sample * softmax mask, summed over k.
// xtb[b][hw][c] (bf16) -> agg_t[b][hw][c] (bf16). Wave = pixel, lanes = 64 x 4 channels.
// grid (1024, B): band = &7 (XCD), sub = >>3; 16 px per block.
__global__ __launch_bounds__(256) void k3_sample(
        const unsigned short* __restrict__ xtb, const float* __restrict__ tmp_t,
        const float* __restrict__ stats, unsigned short* __restrict__ agg_t) {
    __shared__ float lw[16][36];
    __shared__ int   lo[16][36];
    int tid  = threadIdx.x;
    int band = blockIdx.x & 7;
    int sub  = blockIdx.x >> 3;
    int b    = blockIdx.y;
    int px0  = (band * 128 + sub) * 16;

    if (tid < 144) {
        int px = tid / 9, k = tid - px * 9;
        int hw = px0 + px;
        int y  = hw >> 7;
        int xx = hw & (Wx - 1);
        const float* trow = tmp_t + ((size_t)b * HWx + hw) * 32;
        float dy = trow[2 * k];
        float dx = trow[2 * k + 1];
        float lg = trow[18 + k];
        float m  = __expf(lg - stats[(b * Kx + k) * 2]) * stats[(b * Kx + k) * 2 + 1];
        float py = dy + (float)(k / 3 - 1 + y);
        float px_ = dx + (float)(k % 3 - 1 + xx);
        float fy = floorf(py), fx = floorf(px_);
        int y0 = (int)fy, x0 = (int)fx;
        float ly = py - fy, lx = px_ - fx;
        float w00 = (1.f - ly) * (1.f - lx) * m;
        float w01 = (1.f - ly) * lx * m;
        float w10 = ly * (1.f - lx) * m;
        float w11 = ly * lx * m;
        int y1 = y0 + 1, x1 = x0 + 1;
        bool vy0 = (y0 >= 0) & (y0 < Hx), vy1 = (y1 >= 0) & (y1 < Hx);
        bool vx0 = (x0 >= 0) & (x0 < Wx), vx1 = (x1 >= 0) & (x1 < Wx);
        int cy0 = min(max(y0, 0), Hx - 1), cy1 = min(max(y1, 0), Hx - 1);
        int cx0 = min(max(x0, 0), Wx - 1), cx1 = min(max(x1, 0), Wx - 1);
        lw[px][4 * k + 0] = (vy0 && vx0) ? w00 : 0.f;  lo[px][4 * k + 0] = cy0 * Wx + cx0;
        lw[px][4 * k + 1] = (vy0 && vx1) ? w01 : 0.f;  lo[px][4 * k + 1] = cy0 * Wx + cx1;
        lw[px][4 * k + 2] = (vy1 && vx0) ? w10 : 0.f;  lo[px][4 * k + 2] = cy1 * Wx + cx0;
        lw[px][4 * k + 3] = (vy1 && vx1) ? w11 : 0.f;  lo[px][4 * k + 3] = cy1 * Wx + cx1;
    }
    __syncthreads();

    int wave = tid >> 6;
    int lane = tid & 63;
    const unsigned short* xb = xtb + (size_t)b * HWx * Cx + lane * 4;
#pragma unroll 1
    for (int t = 0; t < 4; t++) {
        int px = wave * 4 + t;
        float a0 = 0.f, a1 = 0.f, a2 = 0.f, a3 = 0.f;
#pragma unroll
        for (int j = 0; j < 36; j++) {
            float w  = lw[px][j];
            int  off = lo[px][j];
            uint2 v = *(const uint2*)(xb + (size_t)off * Cx);
            float c0 = __uint_as_float(v.x << 16);
            float c1 = __uint_as_float(v.x & 0xFFFF0000u);
            float c2 = __uint_as_float(v.y << 16);
            float c3 = __uint_as_float(v.y & 0xFFFF0000u);
            a0 += w * c0; a1 += w * c1; a2 += w * c2; a3 += w * c3;
        }
        ushort4 r;
        r.x = f2bf(a0); r.y = f2bf(a1); r.z = f2bf(a2); r.w = f2bf(a3);
        *(ushort4*)(agg_t + ((size_t)b * HWx + px0 + px) * Cx + lane * 4) = r;
    }
}

// out[b,o,hw] = bias[o] + sum_c wq[o,c] * agg_t[b,hw,c]   (bf16 MFMA)
// grid (128, 2, B): block tile 128 hw x 128 oc, 4 waves 2x2, wave tile 64x64.
__global__ __launch_bounds__(256) void k4_mfma(
        const unsigned short* __restrict__ agg_t, const unsigned short* __restrict__ wq,
        const float* __restrict__ bias, float* __restrict__ out) {
    int m0 = blockIdx.x * 128;
    int n0 = blockIdx.y * 128;
    int b  = blockIdx.z;
    __shared__ unsigned short As[128][40];    // [hw][k-local], pad 40 shorts (80 B rows)
    int tid  = threadIdx.x;
    int wave = tid >> 6, lane = tid & 63;
    int wm = wave & 1, wn = wave >> 1;
    int quad = lane >> 4, col = lane & 15;

    f32x4 acc[4][4] = {};

    const unsigned short* arow = agg_t + ((size_t)b * HWx + m0) * Cx;
    int srow = tid >> 1, h = tid & 1;

#pragma unroll 1
    for (int k0 = 0; k0 < Cx; k0 += 32) {
        __syncthreads();
        {   // stage A-tile 128 x 32 (each thread 16 ch = 32 B)
            const unsigned short* src = arow + (size_t)srow * Cx + k0 + h * 16;
            *(uint4*)&As[srow][h * 16]     = *(const uint4*)src;
            *(uint4*)&As[srow][h * 16 + 8] = *(const uint4*)(src + 8);
        }
        __syncthreads();
        bf16x8 a[4], w[4];
#pragma unroll
        for (int mt = 0; mt < 4; mt++)
            a[mt] = *(const bf16x8*)&As[wm * 64 + mt * 16 + col][quad * 8];
#pragma unroll
        for (int nt = 0; nt < 4; nt++)
            w[nt] = *(const bf16x8*)(wq + (size_t)(n0 + wn * 64 + nt * 16 + col) * Cx + k0 + quad * 8);
#pragma unroll
        for (int mt = 0; mt < 4; mt++)
#pragma unroll
            for (int nt = 0; nt < 4; nt++)
                acc[mt][nt] = __builtin_amdgcn_mfma_f32_16x16x32_bf16(a[mt], w[nt], acc[mt][nt], 0, 0, 0);
    }

#pragma unroll
    for (int nt = 0; nt < 4; nt++) {
        int oc = n0 + wn * 64 + nt * 16 + col;
        float bo = bias[oc];
#pragma unroll
        for (int mt = 0; mt < 4; mt++) {
            int hw = m0 + wm * 64 + mt * 16 + quad * 4;
            float4 v;
            v.x = acc[mt][nt][0] + bo; v.y = acc[mt][nt][1] + bo;
            v.z = acc[mt][nt][2] + bo; v.w = acc[mt][nt][3] + bo;
            *(float4*)&out[((size_t)(b * Ox + oc)) * HWx + hw] = v;
        }
    }
}

extern "C" void kernel_launch(void* const* d_in, const int* in_sizes, int n_in,
                              void* d_out, int out_size, void* d_ws, size_t ws_size,
                              hipStream_t stream) {
    const float*    x      = (const float*)d_in[0];
    unsigned short* xbuf   = (unsigned short*)d_in[0];  // reused as bf16 agg_t after last read of x
    const float*    w_off  = (const float*)d_in[1];
    const float*    b_off  = (const float*)d_in[2];
    const float*    weight = (const float*)d_in[3];
    const float*    bias   = (const float*)d_in[4];
    float* out = (float*)d_out;
    float* ws  = (float*)d_ws;

    float*          tmp_t = ws;
    float*          stats = ws + 1048576;
    unsigned short* wbq   = (unsigned short*)(ws + 1048640);
    unsigned short* xtb   = (unsigned short*)(ws + 1085504);
    unsigned short* wq    = (unsigned short*)(ws + 5279808);

    k_init<<<dim3(Bx * HWx * 32 / 256), 256, 0, stream>>>(b_off, tmp_t);
    k_wtr<<<dim3((32 * KK + 255) / 256), 256, 0, stream>>>(w_off, wbq);
    k_wq<<<dim3(Ox * Cx / 256), 256, 0, stream>>>(weight, wq);
    k_tr<<<dim3(HWx / 64, Cx / 64, Bx), 256, 0, stream>>>(x, xtb);
    k1_mfma<<<dim3(128, 9, Bx), 256, 0, stream>>>(xtb, wbq, tmp_t);
    k2_softmax<<<dim3(Bx * Kx), 256, 0, stream>>>(tmp_t, stats);
    // x fully consumed (k_tr); k3 overwrites the x buffer with bf16 agg_t[b][hw][c]
    k3_sample<<<dim3(1024, Bx), 256, 0, stream>>>(xtb, tmp_t, stats, xbuf);
    k4_mfma<<<dim3(128, 2, Bx), 256, 0, stream>>>(xbuf, wq, bias, out);
}

// Round 9
// 184.416 us; speedup vs baseline: 2.8992x; 1.3102x over previous
//
#include <hip/hip_runtime.h>

#define Bx 2
#define Cx 256
#define Hx 128
#define Wx 128
#define HWx (Hx*Wx)     // 16384
#define Ox 256
#define Kx 9
#define NOFF 27         // 3*K offset-conv output channels
#define KK 2304         // 9 taps * 256 channels

typedef __attribute__((ext_vector_type(8))) short bf16x8;
typedef __attribute__((ext_vector_type(4))) float f32x4;

// ws layout (float offsets):
//   tmp_t [0, 1048576)             B*HW*32  (27 used, pad 32; [b][hw][oc])
//   pscr  [1048576, 1050880)       softmax partials: pm[2*64*9], ps[2*64*9]
//   stats [1050880, 1050944)       18*2 (max, 1/sum) padded
//   wbq   [1050944, 1087808)       bf16 W[32][2304], k = tap*256+c
//   xtb   [1087808, 5282112)       bf16 x transposed [b][hw][c] (16.8 MB)
//   wq    [5282112, 5298496)       bf16 weight [o][c] (128 KB)
// k3 writes agg_t[b][hw][c] (bf16) into the x input buffer (restored by harness).

__device__ __forceinline__ unsigned short f2bf(float f) {
    unsigned int u = __float_as_uint(f);
    u = u + 0x7FFFu + ((u >> 16) & 1u);
    return (unsigned short)(u >> 16);
}
__device__ __forceinline__ float bf_lo(unsigned int u) { return __uint_as_float(u << 16); }
__device__ __forceinline__ float bf_hi(unsigned int u) { return __uint_as_float(u & 0xFFFF0000u); }

// wb[oc][tap*256+c] bf16 (rows 27..31 zero) from w_off[oc][c][tap]; wq[o][c] bf16.
__global__ void k_prep(const float* __restrict__ w_off, const float* __restrict__ weight,
                       unsigned short* __restrict__ wb, unsigned short* __restrict__ wq) {
    int i = blockIdx.x * 256 + threadIdx.x;
    if (i < 32 * KK) {
        int oc = i / KK;
        int k  = i - oc * KK;
        int tap = k >> 8;
        int c   = k & 255;
        float v = (oc < NOFF) ? w_off[(oc * Cx + c) * 9 + tap] : 0.f;
        wb[i] = f2bf(v);
    } else {
        int j = i - 32 * KK;
        if (j < Ox * Cx) wq[j] = f2bf(weight[j]);
    }
}

// Transpose+convert x[b][c][hw] -> xtb[b][hw][c] bf16. 64x64 tiles via LDS.
__global__ __launch_bounds__(256) void k_tr(
        const float* __restrict__ x, unsigned short* __restrict__ xtb) {
    __shared__ float tl[64][65];
    int tid = threadIdx.x;
    int hw0 = blockIdx.x * 64;
    int c0  = blockIdx.y * 64;
    int b   = blockIdx.z;
#pragma unroll
    for (int r = 0; r < 4; r++) {
        int cl = r * 16 + (tid >> 4);
        int hl = (tid & 15) * 4;
        const float4 v = *(const float4*)&x[((size_t)(b * Cx + c0 + cl)) * HWx + hw0 + hl];
        tl[cl][hl + 0] = v.x; tl[cl][hl + 1] = v.y; tl[cl][hl + 2] = v.z; tl[cl][hl + 3] = v.w;
    }
    __syncthreads();
#pragma unroll
    for (int r = 0; r < 4; r++) {
        int hl = r * 16 + (tid >> 4);
        int cl = (tid & 15) * 4;
        ushort4 o;
        o.x = f2bf(tl[cl + 0][hl]); o.y = f2bf(tl[cl + 1][hl]);
        o.z = f2bf(tl[cl + 2][hl]); o.w = f2bf(tl[cl + 3][hl]);
        *(ushort4*)&xtb[((size_t)b * HWx + hw0 + hl) * Cx + c0 + cl] = o;
    }
}

// Offset conv, all 9 taps per block, no atomics.
// Block = 1 output row: M=128 px, N=32 oc, K=2304 (4 phases x 64 ch, 9 taps).
// LDS: 3 source rows with +-1 px halo: slots = 3*130, 64 ch (+8 pad) per slot.
// grid (128, B): y = (x&7)*16 + (x>>3)  (XCD row-band locality).
__global__ __launch_bounds__(256) void k1_mfma(
        const unsigned short* __restrict__ xtb, const unsigned short* __restrict__ wb,
        const float* __restrict__ b_off, float* __restrict__ tmp_t) {
    int band = blockIdx.x & 7;
    int sub  = blockIdx.x >> 3;
    int y    = band * 16 + sub;       // output row
    int b    = blockIdx.y;

    __shared__ unsigned short As[390 * 72];   // [slot][64ch + 8 pad], 144 B rows
    int tid  = threadIdx.x;
    int wave = tid >> 6, lane = tid & 63;
    int quad = lane >> 4, col = lane & 15;

    f32x4 acc[2][2] = {};
    const unsigned short* xb = xtb + (size_t)b * HWx * Cx;

#pragma unroll 1
    for (int ph = 0; ph < 4; ph++) {
        __syncthreads();
        // stage 3 rows x 130 (halo) x 64 ch; 16B chunks
        for (int u = tid; u < 3120; u += 256) {
            int slot = u >> 3;
            int ci   = (u & 7) * 8;
            int r = (slot >= 260) ? 2 : (slot >= 130 ? 1 : 0);
            int p = slot - r * 130;
            int yy = y + r - 1;
            int px = p - 1;
            uint4 v = make_uint4(0u, 0u, 0u, 0u);
            if (yy >= 0 && yy < Hx && px >= 0 && px < Wx)
                v = *(const uint4*)(xb + ((size_t)(yy * Wx + px)) * Cx + ph * 64 + ci);
            *(uint4*)&As[slot * 72 + ci] = v;
        }
        __syncthreads();
#pragma unroll
        for (int r = 0; r < 3; r++)
#pragma unroll
        for (int dc = 0; dc < 3; dc++)
#pragma unroll
        for (int s = 0; s < 2; s++) {
            int kl  = s * 32 + quad * 8;
            int tap = r * 3 + dc;
            int kg  = tap * 256 + ph * 64 + kl;
            int base = r * 130 + dc;            // slot for px+dx with halo: px + dc
            bf16x8 a0 = *(const bf16x8*)&As[(base + wave * 32 + col) * 72 + kl];
            bf16x8 a1 = *(const bf16x8*)&As[(base + wave * 32 + 16 + col) * 72 + kl];
            bf16x8 b0 = *(const bf16x8*)(wb + (size_t)col * KK + kg);
            bf16x8 b1 = *(const bf16x8*)(wb + (size_t)(16 + col) * KK + kg);
            acc[0][0] = __builtin_amdgcn_mfma_f32_16x16x32_bf16(a0, b0, acc[0][0], 0, 0, 0);
            acc[0][1] = __builtin_amdgcn_mfma_f32_16x16x32_bf16(a0, b1, acc[0][1], 0, 0, 0);
            acc[1][0] = __builtin_amdgcn_mfma_f32_16x16x32_bf16(a1, b0, acc[1][0], 0, 0, 0);
            acc[1][1] = __builtin_amdgcn_mfma_f32_16x16x32_bf16(a1, b1, acc[1][1], 0, 0, 0);
        }
    }

    float* orow = tmp_t + ((size_t)(b * HWx) + (size_t)y * Wx) * 32;
#pragma unroll
    for (int nt = 0; nt < 2; nt++) {
        int oc = nt * 16 + col;
        float bo = (oc < NOFF) ? b_off[oc] : 0.f;
#pragma unroll
        for (int mt = 0; mt < 2; mt++)
#pragma unroll
            for (int r4 = 0; r4 < 4; r4++) {
                int pxd = wave * 32 + mt * 16 + quad * 4 + r4;
                orow[(size_t)pxd * 32 + oc] = acc[mt][nt][r4] + bo;
            }
    }
}

// Softmax phase A: per-(b,slice of 256 px): partial max & sum-exp for 9 logits.
// pscr: pm[(b*64+s)*9+k], ps[1152 + (b*64+s)*9+k]
__global__ __launch_bounds__(256) void k2a(
        const float* __restrict__ tmp_t, float* __restrict__ pscr) {
    int b  = blockIdx.y;
    int hw = blockIdx.x * 256 + threadIdx.x;
    const float* row = tmp_t + ((size_t)b * HWx + hw) * 32;
    float4 v0 = *(const float4*)(row + 16);
    float4 v1 = *(const float4*)(row + 20);
    float4 v2 = *(const float4*)(row + 24);
    float lv[9] = {v0.z, v0.w, v1.x, v1.y, v1.z, v1.w, v2.x, v2.y, v2.z};

    __shared__ float wm[4][9], wsum[4][9];
    int tid = threadIdx.x;
    int wave = tid >> 6, lane = tid & 63;

    float mx[9];
#pragma unroll
    for (int k = 0; k < 9; k++) mx[k] = lv[k];
    for (int off = 32; off > 0; off >>= 1)
#pragma unroll
        for (int k = 0; k < 9; k++) mx[k] = fmaxf(mx[k], __shfl_down(mx[k], off));
    if (lane == 0)
#pragma unroll
        for (int k = 0; k < 9; k++) wm[wave][k] = mx[k];
    __syncthreads();
    float M[9];
#pragma unroll
    for (int k = 0; k < 9; k++)
        M[k] = fmaxf(fmaxf(wm[0][k], wm[1][k]), fmaxf(wm[2][k], wm[3][k]));
    float sm[9];
#pragma unroll
    for (int k = 0; k < 9; k++) sm[k] = __expf(lv[k] - M[k]);
    for (int off = 32; off > 0; off >>= 1)
#pragma unroll
        for (int k = 0; k < 9; k++) sm[k] += __shfl_down(sm[k], off);
    if (lane == 0)
#pragma unroll
        for (int k = 0; k < 9; k++) wsum[wave][k] = sm[k];
    __syncthreads();
    if (tid < 9) {
        float S = wsum[0][tid] + wsum[1][tid] + wsum[2][tid] + wsum[3][tid];
        int idx = (b * 64 + blockIdx.x) * 9 + tid;
        pscr[idx] = M[tid];
        pscr[1152 + idx] = S;
    }
}

// Softmax phase B: merge 64 slices -> stats[bk] = (max, 1/sum). grid 18, block 64.
__global__ void k2b(const float* __restrict__ pscr, float* __restrict__ stats) {
    int bk = blockIdx.x;
    int b = bk / Kx, k = bk % Kx;
    int s = threadIdx.x;
    int idx = (b * 64 + s) * 9 + k;
    float m = pscr[idx];
    float p = pscr[1152 + idx];
    float M = m;
    for (int off = 32; off > 0; off >>= 1) M = fmaxf(M, __shfl_down(M, off));
    M = __shfl(M, 0);
    float e = p * __expf(m - M);
    for (int off = 32; off > 0; off >>= 1) e += __shfl_down(e, off);
    if (s == 0) { stats[bk * 2] = M; stats[bk * 2 + 1] = 1.f / e; }
}

// Bilinear sample * softmax mask, summed over k.
// xtb[b][hw][c] (bf16) -> agg_t[b][hw][c] (bf16).
// Wave handles 2 px per pass (lane halves), lane covers 8 channels via uint4.
// grid (1024, B): band = &7 (XCD), sub = >>3; 16 px per block.
__global__ __launch_bounds__(256) void k3_sample(
        const unsigned short* __restrict__ xtb, const float* __restrict__ tmp_t,
        const float* __restrict__ stats, unsigned short* __restrict__ agg_t) {
    __shared__ float lw[16][36];
    __shared__ int   lo[16][36];
    int tid  = threadIdx.x;
    int band = blockIdx.x & 7;
    int sub  = blockIdx.x >> 3;
    int b    = blockIdx.y;
    int px0  = (band * 128 + sub) * 16;

    if (tid < 144) {
        int px = tid / 9, k = tid - px * 9;
        int hw = px0 + px;
        int y  = hw >> 7;
        int xx = hw & (Wx - 1);
        const float* trow = tmp_t + ((size_t)b * HWx + hw) * 32;
        float dy = trow[2 * k];
        float dx = trow[2 * k + 1];
        float lg = trow[18 + k];
        float m  = __expf(lg - stats[(b * Kx + k) * 2]) * stats[(b * Kx + k) * 2 + 1];
        float py = dy + (float)(k / 3 - 1 + y);
        float px_ = dx + (float)(k % 3 - 1 + xx);
        float fy = floorf(py), fx = floorf(px_);
        int y0 = (int)fy, x0 = (int)fx;
        float ly = py - fy, lx = px_ - fx;
        float w00 = (1.f - ly) * (1.f - lx) * m;
        float w01 = (1.f - ly) * lx * m;
        float w10 = ly * (1.f - lx) * m;
        float w11 = ly * lx * m;
        int y1 = y0 + 1, x1 = x0 + 1;
        bool vy0 = (y0 >= 0) & (y0 < Hx), vy1 = (y1 >= 0) & (y1 < Hx);
        bool vx0 = (x0 >= 0) & (x0 < Wx), vx1 = (x1 >= 0) & (x1 < Wx);
        int cy0 = min(max(y0, 0), Hx - 1), cy1 = min(max(y1, 0), Hx - 1);
        int cx0 = min(max(x0, 0), Wx - 1), cx1 = min(max(x1, 0), Wx - 1);
        lw[px][4 * k + 0] = (vy0 && vx0) ? w00 : 0.f;  lo[px][4 * k + 0] = cy0 * Wx + cx0;
        lw[px][4 * k + 1] = (vy0 && vx1) ? w01 : 0.f;  lo[px][4 * k + 1] = cy0 * Wx + cx1;
        lw[px][4 * k + 2] = (vy1 && vx0) ? w10 : 0.f;  lo[px][4 * k + 2] = cy1 * Wx + cx0;
        lw[px][4 * k + 3] = (vy1 && vx1) ? w11 : 0.f;  lo[px][4 * k + 3] = cy1 * Wx + cx1;
    }
    __syncthreads();

    int wave = tid >> 6;
    int lane = tid & 63;
    int half = lane >> 5;
    int li   = lane & 31;
    const unsigned short* xb = xtb + (size_t)b * HWx * Cx + li * 8;
#pragma unroll 1
    for (int pass = 0; pass < 2; pass++) {
        int px = wave * 4 + pass * 2 + half;
        float a0 = 0.f, a1 = 0.f, a2 = 0.f, a3 = 0.f;
        float a4 = 0.f, a5 = 0.f, a6 = 0.f, a7 = 0.f;
#pragma unroll
        for (int j = 0; j < 36; j++) {
            float w  = lw[px][j];
            int  off = lo[px][j];
            uint4 v = *(const uint4*)(xb + (size_t)off * Cx);
            a0 += w * bf_lo(v.x); a1 += w * bf_hi(v.x);
            a2 += w * bf_lo(v.y); a3 += w * bf_hi(v.y);
            a4 += w * bf_lo(v.z); a5 += w * bf_hi(v.z);
            a6 += w * bf_lo(v.w); a7 += w * bf_hi(v.w);
        }
        uint4 r;
        r.x = (unsigned)f2bf(a0) | ((unsigned)f2bf(a1) << 16);
        r.y = (unsigned)f2bf(a2) | ((unsigned)f2bf(a3) << 16);
        r.z = (unsigned)f2bf(a4) | ((unsigned)f2bf(a5) << 16);
        r.w = (unsigned)f2bf(a6) | ((unsigned)f2bf(a7) << 16);
        *(uint4*)(agg_t + ((size_t)b * HWx + px0 + px) * Cx + li * 8) = r;
    }
}

// out[b,o,hw] = bias[o] + sum_c wq[o,c] * agg_t[b,hw,c]   (bf16 MFMA)
// grid (128, 2, B): block tile 128 hw x 128 oc, 4 waves 2x2, wave tile 64x64.
__global__ __launch_bounds__(256) void k4_mfma(
        const unsigned short* __restrict__ agg_t, const unsigned short* __restrict__ wq,
        const float* __restrict__ bias, float* __restrict__ out) {
    int m0 = blockIdx.x * 128;
    int n0 = blockIdx.y * 128;
    int b  = blockIdx.z;
    __shared__ unsigned short As[128][40];
    int tid  = threadIdx.x;
    int wave = tid >> 6, lane = tid & 63;
    int wm = wave & 1, wn = wave >> 1;
    int quad = lane >> 4, col = lane & 15;

    f32x4 acc[4][4] = {};

    const unsigned short* arow = agg_t + ((size_t)b * HWx + m0) * Cx;
    int srow = tid >> 1, h = tid & 1;

#pragma unroll 1
    for (int k0 = 0; k0 < Cx; k0 += 32) {
        __syncthreads();
        {
            const unsigned short* src = arow + (size_t)srow * Cx + k0 + h * 16;
            *(uint4*)&As[srow][h * 16]     = *(const uint4*)src;
            *(uint4*)&As[srow][h * 16 + 8] = *(const uint4*)(src + 8);
        }
        __syncthreads();
        bf16x8 a[4], w[4];
#pragma unroll
        for (int mt = 0; mt < 4; mt++)
            a[mt] = *(const bf16x8*)&As[wm * 64 + mt * 16 + col][quad * 8];
#pragma unroll
        for (int nt = 0; nt < 4; nt++)
            w[nt] = *(const bf16x8*)(wq + (size_t)(n0 + wn * 64 + nt * 16 + col) * Cx + k0 + quad * 8);
#pragma unroll
        for (int mt = 0; mt < 4; mt++)
#pragma unroll
            for (int nt = 0; nt < 4; nt++)
                acc[mt][nt] = __builtin_amdgcn_mfma_f32_16x16x32_bf16(a[mt], w[nt], acc[mt][nt], 0, 0, 0);
    }

#pragma unroll
    for (int nt = 0; nt < 4; nt++) {
        int oc = n0 + wn * 64 + nt * 16 + col;
        float bo = bias[oc];
#pragma unroll
        for (int mt = 0; mt < 4; mt++) {
            int hw = m0 + wm * 64 + mt * 16 + quad * 4;
            float4 v;
            v.x = acc[mt][nt][0] + bo; v.y = acc[mt][nt][1] + bo;
            v.z = acc[mt][nt][2] + bo; v.w = acc[mt][nt][3] + bo;
            *(float4*)&out[((size_t)(b * Ox + oc)) * HWx + hw] = v;
        }
    }
}

extern "C" void kernel_launch(void* const* d_in, const int* in_sizes, int n_in,
                              void* d_out, int out_size, void* d_ws, size_t ws_size,
                              hipStream_t stream) {
    const float*    x      = (const float*)d_in[0];
    unsigned short* xbuf   = (unsigned short*)d_in[0];  // reused as bf16 agg_t after last read of x
    const float*    w_off  = (const float*)d_in[1];
    const float*    b_off  = (const float*)d_in[2];
    const float*    weight = (const float*)d_in[3];
    const float*    bias   = (const float*)d_in[4];
    float* out = (float*)d_out;
    float* ws  = (float*)d_ws;

    float*          tmp_t = ws;
    float*          pscr  = ws + 1048576;
    float*          stats = ws + 1050880;
    unsigned short* wbq   = (unsigned short*)(ws + 1050944);
    unsigned short* xtb   = (unsigned short*)(ws + 1087808);
    unsigned short* wq    = (unsigned short*)(ws + 5282112);

    k_prep<<<dim3(544), 256, 0, stream>>>(w_off, weight, wbq, wq);
    k_tr<<<dim3(HWx / 64, Cx / 64, Bx), 256, 0, stream>>>(x, xtb);
    k1_mfma<<<dim3(128, Bx), 256, 0, stream>>>(xtb, wbq, b_off, tmp_t);
    k2a<<<dim3(64, Bx), 256, 0, stream>>>(tmp_t, pscr);
    k2b<<<dim3(Bx * Kx), 64, 0, stream>>>(pscr, stats);
    // x fully consumed (k_tr); k3 overwrites the x buffer with bf16 agg_t[b][hw][c]
    k3_sample<<<dim3(1024, Bx), 256, 0, stream>>>(xtb, tmp_t, stats, xbuf);
    k4_mfma<<<dim3(128, 2, Bx), 256, 0, stream>>>(xbuf, wq, bias, out);
}

// Round 10
// 167.890 us; speedup vs baseline: 3.1846x; 1.0984x over previous
//
#include <hip/hip_runtime.h>
#include <hip/hip_fp16.h>

#define Bx 2
#define Cx 256
#define Hx 128
#define Wx 128
#define HWx (Hx*Wx)     // 16384
#define Ox 256
#define Kx 9
#define NOFF 27         // 3*K offset-conv output channels
#define KK 2304         // 9 taps * 256 channels

typedef __attribute__((ext_vector_type(8))) _Float16 f16x8;
typedef __attribute__((ext_vector_type(4))) float f32x4;

// ws layout (float offsets):
//   tmp_t [0, 1048576)             B*HW*32  (27 used, pad 32; [b][hw][oc])
//   pscr  [1048576, 1050880)       softmax partials: pm[2*64*9], ps[1152+...]
//   stats [1050880, 1050944)       18*2 (max, 1/sum) padded
//   wbq   [1050944, 1087808)       f16 W[32][2304], k = tap*256+c
//   xtb   [1087808, 5282112)       f16 x transposed [b][hw][c] (16.8 MB)
//   wq    [5282112, 5314880)       f16 weight [o][c] (128 KB)

__device__ __forceinline__ unsigned short f2h(float f) {
    return __half_as_ushort(__float2half_rn(f));
}

// wb[oc][tap*256+c] f16 (rows 27..31 zero) from w_off[oc][c][tap]; wq[o][c] f16.
__global__ void k_prep(const float* __restrict__ w_off, const float* __restrict__ weight,
                       unsigned short* __restrict__ wb, unsigned short* __restrict__ wq) {
    int i = blockIdx.x * 256 + threadIdx.x;
    if (i < 32 * KK) {
        int oc = i / KK;
        int k  = i - oc * KK;
        int tap = k >> 8;
        int c   = k & 255;
        float v = (oc < NOFF) ? w_off[(oc * Cx + c) * 9 + tap] : 0.f;
        wb[i] = f2h(v);
    } else {
        int j = i - 32 * KK;
        if (j < Ox * Cx) wq[j] = f2h(weight[j]);
    }
}

// Transpose+convert x[b][c][hw] -> xtb[b][hw][c] f16. 64x64 tiles via LDS.
__global__ __launch_bounds__(256) void k_tr(
        const float* __restrict__ x, unsigned short* __restrict__ xtb) {
    __shared__ float tl[64][65];
    int tid = threadIdx.x;
    int hw0 = blockIdx.x * 64;
    int c0  = blockIdx.y * 64;
    int b   = blockIdx.z;
#pragma unroll
    for (int r = 0; r < 4; r++) {
        int cl = r * 16 + (tid >> 4);
        int hl = (tid & 15) * 4;
        const float4 v = *(const float4*)&x[((size_t)(b * Cx + c0 + cl)) * HWx + hw0 + hl];
        tl[cl][hl + 0] = v.x; tl[cl][hl + 1] = v.y; tl[cl][hl + 2] = v.z; tl[cl][hl + 3] = v.w;
    }
    __syncthreads();
#pragma unroll
    for (int r = 0; r < 4; r++) {
        int hl = r * 16 + (tid >> 4);
        int cl = (tid & 15) * 4;
        ushort4 o;
        o.x = f2h(tl[cl + 0][hl]); o.y = f2h(tl[cl + 1][hl]);
        o.z = f2h(tl[cl + 2][hl]); o.w = f2h(tl[cl + 3][hl]);
        *(ushort4*)&xtb[((size_t)b * HWx + hw0 + hl) * Cx + c0 + cl] = o;
    }
}

// Offset conv, all 9 taps per block, no atomics. f16 MFMA.
// Block = 1 output row: M=128 px, N=32 oc, K=2304 (4 phases x 64 ch, 9 taps).
// grid (128, B): y = (x&7)*16 + (x>>3)  (XCD row-band locality).
__global__ __launch_bounds__(256) void k1_mfma(
        const unsigned short* __restrict__ xtb, const unsigned short* __restrict__ wb,
        const float* __restrict__ b_off, float* __restrict__ tmp_t) {
    int band = blockIdx.x & 7;
    int sub  = blockIdx.x >> 3;
    int y    = band * 16 + sub;       // output row
    int b    = blockIdx.y;

    __shared__ unsigned short As[390 * 72];   // [slot][64ch + 8 pad]
    int tid  = threadIdx.x;
    int wave = tid >> 6, lane = tid & 63;
    int quad = lane >> 4, col = lane & 15;

    f32x4 acc[2][2] = {};
    const unsigned short* xb = xtb + (size_t)b * HWx * Cx;

#pragma unroll 1
    for (int ph = 0; ph < 4; ph++) {
        __syncthreads();
        for (int u = tid; u < 3120; u += 256) {
            int slot = u >> 3;
            int ci   = (u & 7) * 8;
            int r = (slot >= 260) ? 2 : (slot >= 130 ? 1 : 0);
            int p = slot - r * 130;
            int yy = y + r - 1;
            int px = p - 1;
            uint4 v = make_uint4(0u, 0u, 0u, 0u);
            if (yy >= 0 && yy < Hx && px >= 0 && px < Wx)
                v = *(const uint4*)(xb + ((size_t)(yy * Wx + px)) * Cx + ph * 64 + ci);
            *(uint4*)&As[slot * 72 + ci] = v;
        }
        __syncthreads();
#pragma unroll
        for (int r = 0; r < 3; r++)
#pragma unroll
        for (int dc = 0; dc < 3; dc++)
#pragma unroll
        for (int s = 0; s < 2; s++) {
            int kl  = s * 32 + quad * 8;
            int tap = r * 3 + dc;
            int kg  = tap * 256 + ph * 64 + kl;
            int base = r * 130 + dc;
            f16x8 a0 = *(const f16x8*)&As[(base + wave * 32 + col) * 72 + kl];
            f16x8 a1 = *(const f16x8*)&As[(base + wave * 32 + 16 + col) * 72 + kl];
            f16x8 b0 = *(const f16x8*)(wb + (size_t)col * KK + kg);
            f16x8 b1 = *(const f16x8*)(wb + (size_t)(16 + col) * KK + kg);
            acc[0][0] = __builtin_amdgcn_mfma_f32_16x16x32_f16(a0, b0, acc[0][0], 0, 0, 0);
            acc[0][1] = __builtin_amdgcn_mfma_f32_16x16x32_f16(a0, b1, acc[0][1], 0, 0, 0);
            acc[1][0] = __builtin_amdgcn_mfma_f32_16x16x32_f16(a1, b0, acc[1][0], 0, 0, 0);
            acc[1][1] = __builtin_amdgcn_mfma_f32_16x16x32_f16(a1, b1, acc[1][1], 0, 0, 0);
        }
    }

    float* orow = tmp_t + ((size_t)(b * HWx) + (size_t)y * Wx) * 32;
#pragma unroll
    for (int nt = 0; nt < 2; nt++) {
        int oc = nt * 16 + col;
        float bo = (oc < NOFF) ? b_off[oc] : 0.f;
#pragma unroll
        for (int mt = 0; mt < 2; mt++)
#pragma unroll
            for (int r4 = 0; r4 < 4; r4++) {
                int pxd = wave * 32 + mt * 16 + quad * 4 + r4;
                orow[(size_t)pxd * 32 + oc] = acc[mt][nt][r4] + bo;
            }
    }
}

// Softmax phase A: per-(b,slice of 256 px): partial max & sum-exp for 9 logits.
__global__ __launch_bounds__(256) void k2a(
        const float* __restrict__ tmp_t, float* __restrict__ pscr) {
    int b  = blockIdx.y;
    int hw = blockIdx.x * 256 + threadIdx.x;
    const float* row = tmp_t + ((size_t)b * HWx + hw) * 32;
    float4 v0 = *(const float4*)(row + 16);
    float4 v1 = *(const float4*)(row + 20);
    float4 v2 = *(const float4*)(row + 24);
    float lv[9] = {v0.z, v0.w, v1.x, v1.y, v1.z, v1.w, v2.x, v2.y, v2.z};

    __shared__ float wm[4][9], wsum[4][9];
    int tid = threadIdx.x;
    int wave = tid >> 6, lane = tid & 63;

    float mx[9];
#pragma unroll
    for (int k = 0; k < 9; k++) mx[k] = lv[k];
    for (int off = 32; off > 0; off >>= 1)
#pragma unroll
        for (int k = 0; k < 9; k++) mx[k] = fmaxf(mx[k], __shfl_down(mx[k], off));
    if (lane == 0)
#pragma unroll
        for (int k = 0; k < 9; k++) wm[wave][k] = mx[k];
    __syncthreads();
    float M[9];
#pragma unroll
    for (int k = 0; k < 9; k++)
        M[k] = fmaxf(fmaxf(wm[0][k], wm[1][k]), fmaxf(wm[2][k], wm[3][k]));
    float sm[9];
#pragma unroll
    for (int k = 0; k < 9; k++) sm[k] = __expf(lv[k] - M[k]);
    for (int off = 32; off > 0; off >>= 1)
#pragma unroll
        for (int k = 0; k < 9; k++) sm[k] += __shfl_down(sm[k], off);
    if (lane == 0)
#pragma unroll
        for (int k = 0; k < 9; k++) wsum[wave][k] = sm[k];
    __syncthreads();
    if (tid < 9) {
        float S = wsum[0][tid] + wsum[1][tid] + wsum[2][tid] + wsum[3][tid];
        int idx = (b * 64 + blockIdx.x) * 9 + tid;
        pscr[idx] = M[tid];
        pscr[1152 + idx] = S;
    }
}

// Softmax phase B: merge 64 slices -> stats[bk] = (max, 1/sum). grid 18, block 64.
__global__ void k2b(const float* __restrict__ pscr, float* __restrict__ stats) {
    int bk = blockIdx.x;
    int b = bk / Kx, k = bk % Kx;
    int s = threadIdx.x;
    int idx = (b * 64 + s) * 9 + k;
    float m = pscr[idx];
    float p = pscr[1152 + idx];
    float M = m;
    for (int off = 32; off > 0; off >>= 1) M = fmaxf(M, __shfl_down(M, off));
    M = __shfl(M, 0);
    float e = p * __expf(m - M);
    for (int off = 32; off > 0; off >>= 1) e += __shfl_down(e, off);
    if (s == 0) { stats[bk * 2] = M; stats[bk * 2 + 1] = 1.f / e; }
}

// Fused sample + 1x1 conv. Block = 64 px, all 256 ch, all 256 oc.
// Phase 1: bilinear sample * mask (x256 scale), packed f16 FMA, -> LDS As[64][264].
// Phase 2: MFMA GEMM M=64 px x N=256 oc x K=256 c; fused bias; float4 stores.
// grid (256, B): band = &7 (XCD), sub = >>3; px0 = (band*32+sub)*64.
__global__ __launch_bounds__(256) void k35_fused(
        const unsigned short* __restrict__ xtb, const float* __restrict__ tmp_t,
        const float* __restrict__ stats, const unsigned short* __restrict__ wq,
        const float* __restrict__ bias, float* __restrict__ out) {
    __shared__ __half2 lwh[64][36];           // (w,w) packed, x256 scale
    __shared__ int     lo[64][36];
    __shared__ unsigned short As[64][264];    // sampled f16, stride 132 dw = 4 mod 32
    int tid  = threadIdx.x;
    int band = blockIdx.x & 7;
    int sub  = blockIdx.x >> 3;
    int b    = blockIdx.y;
    int px0  = (band * 32 + sub) * 64;

    for (int u = tid; u < 576; u += 256) {
        int px = u / 9, k = u - px * 9;
        int hw = px0 + px;
        int y  = hw >> 7;
        int xx = hw & (Wx - 1);
        const float* trow = tmp_t + ((size_t)b * HWx + hw) * 32;
        float dy = trow[2 * k];
        float dx = trow[2 * k + 1];
        float lg = trow[18 + k];
        float m  = __expf(lg - stats[(b * Kx + k) * 2]) * stats[(b * Kx + k) * 2 + 1] * 256.f;
        float py = dy + (float)(k / 3 - 1 + y);
        float px_ = dx + (float)(k % 3 - 1 + xx);
        float fy = floorf(py), fx = floorf(px_);
        int y0 = (int)fy, x0 = (int)fx;
        float ly = py - fy, lx = px_ - fx;
        float w00 = (1.f - ly) * (1.f - lx) * m;
        float w01 = (1.f - ly) * lx * m;
        float w10 = ly * (1.f - lx) * m;
        float w11 = ly * lx * m;
        int y1 = y0 + 1, x1 = x0 + 1;
        bool vy0 = (y0 >= 0) & (y0 < Hx), vy1 = (y1 >= 0) & (y1 < Hx);
        bool vx0 = (x0 >= 0) & (x0 < Wx), vx1 = (x1 >= 0) & (x1 < Wx);
        int cy0 = min(max(y0, 0), Hx - 1), cy1 = min(max(y1, 0), Hx - 1);
        int cx0 = min(max(x0, 0), Wx - 1), cx1 = min(max(x1, 0), Wx - 1);
        float a00 = (vy0 && vx0) ? w00 : 0.f;
        float a01 = (vy0 && vx1) ? w01 : 0.f;
        float a10 = (vy1 && vx0) ? w10 : 0.f;
        float a11 = (vy1 && vx1) ? w11 : 0.f;
        lwh[px][4 * k + 0] = __half2half2(__float2half_rn(a00));  lo[px][4 * k + 0] = cy0 * Wx + cx0;
        lwh[px][4 * k + 1] = __half2half2(__float2half_rn(a01));  lo[px][4 * k + 1] = cy0 * Wx + cx1;
        lwh[px][4 * k + 2] = __half2half2(__float2half_rn(a10));  lo[px][4 * k + 2] = cy1 * Wx + cx0;
        lwh[px][4 * k + 3] = __half2half2(__float2half_rn(a11));  lo[px][4 * k + 3] = cy1 * Wx + cx1;
    }
    __syncthreads();

    int wave = tid >> 6;
    int lane = tid & 63;
    int half = lane >> 5;
    int li   = lane & 31;
    const unsigned short* xb = xtb + (size_t)b * HWx * Cx + li * 8;
    const __half2 uns = __half2half2(__float2half_rn(1.f / 256.f));
#pragma unroll 1
    for (int pass = 0; pass < 8; pass++) {
        int px = wave * 16 + pass * 2 + half;
        __half2 a0 = __half2half2(__ushort_as_half(0));
        __half2 a1 = a0, a2 = a0, a3 = a0;
#pragma unroll
        for (int j = 0; j < 36; j++) {
            __half2 w = lwh[px][j];
            int   off = lo[px][j];
            uint4 v = *(const uint4*)(xb + (size_t)off * Cx);
            a0 = __hfma2(w, *(__half2*)&v.x, a0);
            a1 = __hfma2(w, *(__half2*)&v.y, a1);
            a2 = __hfma2(w, *(__half2*)&v.z, a2);
            a3 = __hfma2(w, *(__half2*)&v.w, a3);
        }
        a0 = __hmul2(a0, uns); a1 = __hmul2(a1, uns);
        a2 = __hmul2(a2, uns); a3 = __hmul2(a3, uns);
        uint4 r;
        r.x = *(unsigned*)&a0; r.y = *(unsigned*)&a1;
        r.z = *(unsigned*)&a2; r.w = *(unsigned*)&a3;
        *(uint4*)&As[px][li * 8] = r;
    }
    __syncthreads();

    // GEMM: wave covers oc [wave*64, wave*64+64), all 64 px.
    int quad = lane >> 4, col = lane & 15;
    f32x4 acc[4][4] = {};
#pragma unroll
    for (int ki = 0; ki < 8; ki++) {
        int k0 = ki * 32;
        f16x8 a[4], w[4];
#pragma unroll
        for (int mt = 0; mt < 4; mt++)
            a[mt] = *(const f16x8*)&As[mt * 16 + col][k0 + quad * 8];
#pragma unroll
        for (int nt = 0; nt < 4; nt++)
            w[nt] = *(const f16x8*)(wq + (size_t)(wave * 64 + nt * 16 + col) * Cx + k0 + quad * 8);
#pragma unroll
        for (int mt = 0; mt < 4; mt++)
#pragma unroll
            for (int nt = 0; nt < 4; nt++)
                acc[mt][nt] = __builtin_amdgcn_mfma_f32_16x16x32_f16(a[mt], w[nt], acc[mt][nt], 0, 0, 0);
    }

#pragma unroll
    for (int nt = 0; nt < 4; nt++) {
        int oc = wave * 64 + nt * 16 + col;
        float bo = bias[oc];
#pragma unroll
        for (int mt = 0; mt < 4; mt++) {
            int hw = px0 + mt * 16 + quad * 4;
            float4 v;
            v.x = acc[mt][nt][0] + bo; v.y = acc[mt][nt][1] + bo;
            v.z = acc[mt][nt][2] + bo; v.w = acc[mt][nt][3] + bo;
            *(float4*)&out[((size_t)(b * Ox + oc)) * HWx + hw] = v;
        }
    }
}

extern "C" void kernel_launch(void* const* d_in, const int* in_sizes, int n_in,
                              void* d_out, int out_size, void* d_ws, size_t ws_size,
                              hipStream_t stream) {
    const float*    x      = (const float*)d_in[0];
    const float*    w_off  = (const float*)d_in[1];
    const float*    b_off  = (const float*)d_in[2];
    const float*    weight = (const float*)d_in[3];
    const float*    bias   = (const float*)d_in[4];
    float* out = (float*)d_out;
    float* ws  = (float*)d_ws;

    float*          tmp_t = ws;
    float*          pscr  = ws + 1048576;
    float*          stats = ws + 1050880;
    unsigned short* wbq   = (unsigned short*)(ws + 1050944);
    unsigned short* xtb   = (unsigned short*)(ws + 1087808);
    unsigned short* wq    = (unsigned short*)(ws + 5282112);

    k_prep<<<dim3(544), 256, 0, stream>>>(w_off, weight, wbq, wq);
    k_tr<<<dim3(HWx / 64, Cx / 64, Bx), 256, 0, stream>>>(x, xtb);
    k1_mfma<<<dim3(128, Bx), 256, 0, stream>>>(xtb, wbq, b_off, tmp_t);
    k2a<<<dim3(64, Bx), 256, 0, stream>>>(tmp_t, pscr);
    k2b<<<dim3(Bx * Kx), 64, 0, stream>>>(pscr, stats);
    k35_fused<<<dim3(256, Bx), 256, 0, stream>>>(xtb, tmp_t, stats, wq, bias, out);
}